// Round 7
// baseline (273.013 us; speedup 1.0000x reference)
//
#include <hip/hip_runtime.h>
#include <math.h>

#define NBATCH 8
#define NFRAME 400
#define NHARM  100
#define NBAND  65
#define SRATE  16000
#define BLK    128
#define NSAMP  (NFRAME*BLK)      // 51200 samples per batch
#define IMPN   16384             // impulse padded to 64*256
#define PI_D   3.14159265358979323846

// workspace layout (byte offsets, all 16B aligned)
#define OFF_PREFIX 0             // double[8*400]        = 25600 B
#define OFF_SIG    2944000       // float[8*51200]       = 1638400 B
#define OFF_IMP    4582400       // float[16384]         = 65536 B
#define OFF_PART   4647936       // float[8*25*16*2048]  = 26214400 B
#define WS_NEED    (OFF_PART + 26214400)

__device__ __forceinline__ float scale_fn(float x) {
    float s = 1.0f / (1.0f + expf(-x));
    return 2.0f * powf(s, 2.3025851f) + 1e-7f;   // log(10) = 2.302585093
}

// --- exclusive prefix sum of pitch per batch (fp64), 8 serial chains ---
__global__ void k_prefix(const float* __restrict__ pitch, double* __restrict__ prefix) {
    int b = threadIdx.x;
    if (b < NBATCH) {
        double s = 0.0;
        const float* p = pitch + b * NFRAME;
        double* o = prefix + b * NFRAME;
        for (int f = 0; f < NFRAME; ++f) { o[f] = s; s += (double)p[f]; }
    }
}

// --- reverb impulse: imp[0]=1; imp[t]=rn[t]*exp(-c*t)*sigmoid(wet), zero-pad to 16384 ---
__global__ void k_imp(const float* __restrict__ rn, const float* __restrict__ decay,
                      const float* __restrict__ wet, float* __restrict__ imp) {
    int t = blockIdx.x * blockDim.x + threadIdx.x;
    if (t >= IMPN) return;
    double c  = log1p(exp(-(double)decay[0])) * (500.0 / (double)SRATE); // per-sample rate
    double wg = 1.0 / (1.0 + exp(-(double)wet[0]));
    float v;
    if (t == 0)            v = 1.0f;
    else if (t < SRATE)    v = rn[t] * (float)(exp(-c * (double)t) * wg);
    else                   v = 0.0f;
    imp[t] = v;
}

// --- fused per-(b,f) frame processing + harmonic synth -> signal ---
// Phase 1 (old k_frame): normalized harmonic amps + filtered-noise ir + nz,
// all kept in LDS. Phase 2 (old k_harm): sin-sum + add nz, write sig.
__global__ __launch_bounds__(128) void k_synth(const float* __restrict__ amp_param,
                                               const float* __restrict__ noise_param,
                                               const float* __restrict__ pitch,
                                               const float* __restrict__ noise,
                                               const double* __restrict__ prefix,
                                               float* __restrict__ sig) {
    __shared__ float s_famps[NHARM];   // normalized amps (phase-2 input)
    __shared__ float s_amps[NHARM];    // masked raw amps
    __shared__ float s_np[NBAND];
    __shared__ float s_ct[BLK];
    __shared__ float s_ir[BLK];
    __shared__ float s_noise[BLK];
    __shared__ float s_nz[BLK];
    __shared__ float s_red[BLK];
    __shared__ float s_total;

    int bf = blockIdx.x;
    int tid = threadIdx.x;
    float pf = pitch[bf];

    if (tid < NHARM + 1) {
        float p = scale_fn(amp_param[bf * (NHARM + 1) + tid]);
        if (tid == 0) s_total = p;
        else {
            // aa = (pitch*k < sr/2) + 1e-4  -> 1.0001 or 0.0001, k = tid
            float aa = (pf * (float)tid < 8000.0f) ? 1.0001f : 0.0001f;
            s_amps[tid - 1] = p * aa;
        }
    }
    if (tid < NBAND) s_np[tid] = scale_fn(noise_param[bf * NBAND + tid] - 5.0f);
    s_ct[tid]    = (float)cos(2.0 * PI_D * (double)tid / 128.0);
    s_noise[tid] = noise[bf * BLK + tid];
    __syncthreads();

    // ir[n] = irfft(np)[n] * (0.5 + 0.5*cos(2*pi*n/128))  (roll/hann/roll collapsed)
    float irv;
    {
        int n = tid;
        float a = s_np[0];
        #pragma unroll
        for (int k = 1; k < NBAND - 1; ++k) a += 2.0f * s_np[k] * s_ct[(k * n) & 127];
        a += s_np[NBAND - 1] * s_ct[(64 * n) & 127];
        a *= (1.0f / 128.0f);
        a *= 0.5f + 0.5f * s_ct[n];
        irv = a;
    }

    // sum of masked amps (tree reduce over 128, entries >=100 are 0)
    s_red[tid] = (tid < NHARM) ? s_amps[tid] : 0.0f;
    __syncthreads();
    for (int s = 64; s > 0; s >>= 1) {
        if (tid < s) s_red[tid] += s_red[tid + s];
        __syncthreads();
    }
    if (tid < NHARM) s_famps[tid] = s_amps[tid] / s_red[0] * s_total;
    s_ir[tid] = irv;
    __syncthreads();

    // nz[p] = sum_{m<=p} noise[m] * ir[p-m]
    float nzv = 0.0f;
    for (int m = 0; m <= tid; ++m) nzv += s_noise[m] * s_ir[tid - m];
    s_nz[tid] = nzv;
    __syncthreads();

    // harmonic synth: omega[n] = 2pi/sr * (128*prefix_excl + (r+1)*pitch)
    double om = (2.0 * PI_D / (double)SRATE) *
                (128.0 * prefix[bf] + (double)(tid + 1) * (double)pf);
    float th = (float)fmod(om, 2.0 * PI_D);   // exact for integer-k harmonics
    float h = 0.0f;
    #pragma unroll 4
    for (int k = 1; k <= NHARM; ++k) h += sinf(th * (float)k) * s_famps[k - 1];
    sig[bf * BLK + tid] = h + s_nz[tid];
}

// --- reverb: out[p] = sum_{t<=p, t<16000} imp[t]*sig[p-t] ---
// Sliding-window + tap-split. Each thread owns 16 CONSECUTIVE outputs; per
// 4-tap group: 1 new ds_read_b128 (XOR-swizzled LDS) feeds 64 FMAs, with an
// 8-slot float4 REGISTER-circular window (period 8 == unroll 8 -> all slot
// indices static, zero shift-movs). Partials to part[b][tile][seg][2048]
// (plain stores, no cross-XCD atomics); k_reduce sums active segs.
#define RTILE 2048     // outputs per tile (128 thr x 16)
#define RCT   256      // taps per chunk
#define RKTH  128      // threads
#define RCH   4        // chunks per block segment
#define RMAXSEG 16     // ceil(63 / RCH)
#define NTILES (NSAMP / RTILE)   // 25 per batch
#define RWIN  (RTILE + RCT)      // 2304 floats
#define RWIN4 (RWIN / 4)         // 576 float4 (multiple of 8 -> swizzle closed)

__device__ __forceinline__ int swz4(int F) { return F ^ ((F >> 3) & 7); }

template <int ATOMIC>
__global__ __launch_bounds__(RKTH) void k_reverb4(const float* __restrict__ sig,
                                                  const float* __restrict__ imp,
                                                  float* __restrict__ dst) {
    __shared__ __align__(16) float s_sig[RWIN];

    int bid  = blockIdx.x;
    int seg  = bid % RMAXSEG;
    int bt   = bid / RMAXSEG;
    int b    = bt / NTILES;
    int tile = bt % NTILES;
    int P0   = tile * RTILE;
    int nch  = (P0 + RTILE) / RCT;             // taps needed: t <= P0+RTILE-1
    if (nch > 63) nch = 63;                    // imp zero beyond 16128
    int c0 = seg * RCH;
    if (c0 >= nch) return;
    int c1 = c0 + RCH; if (c1 > nch) c1 = nch;

    int tid = threadIdx.x;
    const float* sb = sig + b * NSAMP;

    float af[16];
    #pragma unroll
    for (int o = 0; o < 16; ++o) af[o] = 0.f;

    int Fbase = 4 * tid + (RCT / 4 - 1);       // 4*tid + 63

    for (int c = c0; c < c1; ++c) {
        int T0 = c * RCT;
        int W0 = P0 - T0 - RCT;                // logical window float l <-> sig[W0 + l]
        if (W0 >= 0) {
            #pragma unroll
            for (int it = 0; it < 5; ++it) {
                int F = tid + RKTH * it;
                if (F < RWIN4)
                    *reinterpret_cast<float4*>(&s_sig[4 * swz4(F)]) =
                        *reinterpret_cast<const float4*>(&sb[W0 + 4 * F]);
            }
        } else {
            for (int l = tid; l < RWIN; l += RKTH) {
                int idx = W0 + l;
                float v = (idx >= 0) ? sb[idx] : 0.0f;
                s_sig[4 * swz4(l >> 2) + (l & 3)] = v;
            }
        }
        __syncthreads();

        const float4* imp4 = reinterpret_cast<const float4*>(imp + T0);  // uniform -> s_load

        // register-circular window: slot(F) = (Fbase - F) & 7
        float4 R[8];
        #pragma unroll
        for (int i = 0; i < 5; ++i)
            R[(8 - i) & 7] = *reinterpret_cast<const float4*>(&s_sig[4 * swz4(Fbase + i)]);

        #pragma unroll
        for (int gg = 0; gg < RCT / 4; gg += 8) {
            #pragma unroll
            for (int q = 0; q < 8; ++q) {
                const int g = gg + q;
                float4 iq = imp4[g];
                // window floats w[m], m in [0,20): f4 i=m>>2 at slot (q-i)&7
                const float4 b0 = R[q & 7];
                const float4 b1 = R[(q + 7) & 7];
                const float4 b2 = R[(q + 6) & 7];
                const float4 b3 = R[(q + 5) & 7];
                const float4 b4 = R[(q + 4) & 7];
                float w[20];
                w[ 0]=b0.x; w[ 1]=b0.y; w[ 2]=b0.z; w[ 3]=b0.w;
                w[ 4]=b1.x; w[ 5]=b1.y; w[ 6]=b1.z; w[ 7]=b1.w;
                w[ 8]=b2.x; w[ 9]=b2.y; w[10]=b2.z; w[11]=b2.w;
                w[12]=b3.x; w[13]=b3.y; w[14]=b3.z; w[15]=b3.w;
                w[16]=b4.x; w[17]=b4.y; w[18]=b4.z; w[19]=b4.w;
                #pragma unroll
                for (int o = 0; o < 16; ++o) {
                    af[o] += iq.x * w[o + 4];
                    af[o] += iq.y * w[o + 3];
                    af[o] += iq.z * w[o + 2];
                    af[o] += iq.w * w[o + 1];
                }
                if (g < RCT / 4 - 1)   // next group's data F = Fbase-1-g -> slot (g+1)&7
                    R[(q + 1) & 7] =
                        *reinterpret_cast<const float4*>(&s_sig[4 * swz4(Fbase - 1 - g)]);
            }
        }
        __syncthreads();
    }

    if (ATOMIC) {
        float* ob = dst + b * NSAMP + P0 + 16 * tid;
        #pragma unroll
        for (int o = 0; o < 16; ++o) atomicAdd(&ob[o], af[o]);
    } else {
        // part[b][tile][seg][2048], plain coalesced stores
        float* pb = dst + (((b * NTILES + tile) * RMAXSEG + seg) * RTILE) + 16 * tid;
        #pragma unroll
        for (int o = 0; o < 4; ++o)
            *reinterpret_cast<float4*>(&pb[4 * o]) =
                *reinterpret_cast<float4*>(&af[4 * o]);
    }
}

// --- sum active segs: out[b][tile*2048 + x] = sum_s part[b][tile][s][x] ---
__global__ __launch_bounds__(256) void k_reduce(const float* __restrict__ part,
                                                float* __restrict__ out) {
    int q = blockIdx.x * blockDim.x + threadIdx.x;   // float4 index, 102400 total
    int b    = q / (NSAMP / 4);
    int rem  = q % (NSAMP / 4);
    int tile = rem / (RTILE / 4);
    int off4 = rem % (RTILE / 4);
    int nch  = (8 * (tile + 1) < 63) ? 8 * (tile + 1) : 63;
    int nsg  = (nch + RCH - 1) / RCH;

    const float4* p4 = reinterpret_cast<const float4*>(part) +
                       ((b * NTILES + tile) * RMAXSEG) * (RTILE / 4) + off4;
    float4 s = {0.f, 0.f, 0.f, 0.f};
    for (int sgi = 0; sgi < nsg; ++sgi) {
        float4 v = p4[sgi * (RTILE / 4)];
        s.x += v.x; s.y += v.y; s.z += v.z; s.w += v.w;
    }
    reinterpret_cast<float4*>(out)[q] = s;
}

extern "C" void kernel_launch(void* const* d_in, const int* in_sizes, int n_in,
                              void* d_out, int out_size, void* d_ws, size_t ws_size,
                              hipStream_t stream) {
    const float* amp_param   = (const float*)d_in[0];
    const float* noise_param = (const float*)d_in[1];
    const float* pitch       = (const float*)d_in[2];
    const float* noise       = (const float*)d_in[3];
    const float* rn          = (const float*)d_in[4];
    const float* decay       = (const float*)d_in[5];
    const float* wet         = (const float*)d_in[6];
    float* out = (float*)d_out;

    char* ws = (char*)d_ws;
    double* prefix = (double*)(ws + OFF_PREFIX);
    float*  sig    = (float*)(ws + OFF_SIG);
    float*  imp    = (float*)(ws + OFF_IMP);
    float*  part   = (float*)(ws + OFF_PART);

    k_prefix<<<dim3(1), dim3(64), 0, stream>>>(pitch, prefix);
    k_imp<<<dim3(IMPN / 256), dim3(256), 0, stream>>>(rn, decay, wet, imp);
    k_synth<<<dim3(NBATCH * NFRAME), dim3(128), 0, stream>>>(amp_param, noise_param, pitch, noise, prefix, sig);

    if (ws_size >= (size_t)WS_NEED) {
        k_reverb4<0><<<dim3(NBATCH * NTILES * RMAXSEG), dim3(RKTH), 0, stream>>>(sig, imp, part);
        k_reduce<<<dim3(NBATCH * NSAMP / 4 / 256), dim3(256), 0, stream>>>(part, out);
    } else {
        hipMemsetAsync(out, 0, (size_t)out_size * sizeof(float), stream);
        k_reverb4<1><<<dim3(NBATCH * NTILES * RMAXSEG), dim3(RKTH), 0, stream>>>(sig, imp, out);
    }
}

// Round 8
// 134.074 us; speedup vs baseline: 2.0363x; 2.0363x over previous
//
#include <hip/hip_runtime.h>
#include <math.h>

#define NBATCH 8
#define NFRAME 400
#define NHARM  100
#define NBAND  65
#define SRATE  16000
#define BLK    128
#define NSAMP  (NFRAME*BLK)      // 51200 samples per batch
#define IMPN   16384             // impulse padded to 8*2048
#define PI_D   3.14159265358979323846

// FFT convolution params: overlap-save, FFT 4096, hop 2048, 8 imp partitions
#define FFTN   4096
#define HOP    2048
#define NPART  8
#define NHOPS  (NSAMP / HOP)     // 25 per batch

// workspace layout (byte offsets, 8B aligned)
#define OFF_PREFIX 0             // double[8*400]            = 25600 B
#define OFF_SIG    25600         // float[8*51200]           = 1638400 B
#define OFF_IMP    1664000       // float[16384]             = 65536 B
#define OFF_H      1729536       // float2[8][4096]          = 262144 B
#define OFF_X      1991680       // float2[8*25][4096]       = 6553600 B
// end 8545280 (~8.5 MB)

typedef float2 cplx;

__device__ __forceinline__ cplx cmul(cplx a, cplx b) {
    return make_float2(a.x * b.x - a.y * b.y, a.x * b.y + a.y * b.x);
}

// ---- 4096-pt in-place complex FFT in LDS, 256 threads ----
// DIF (Gentleman-Sande): natural input -> bit-reversed output. Use SIGN=-1 (forward).
template <int SIGN>
__device__ __forceinline__ void fft_dif_4096(cplx* A, int tid) {
    for (int t = 12; t >= 1; --t) {
        const int len = 1 << t, half = 1 << (t - 1);
        __syncthreads();
        #pragma unroll
        for (int it = 0; it < 8; ++it) {
            int i = tid + (it << 8);               // butterfly idx [0,2048)
            int j = i & (half - 1);
            int a = ((i >> (t - 1)) << t) + j;
            int b = a + half;
            float ang = (float)(2.0 * PI_D) * (float)j / (float)len;
            float sn, cs; __sincosf(ang, &sn, &cs);
            cplx w = make_float2(cs, (float)SIGN * sn);
            cplx u = A[a], v = A[b];
            A[a] = make_float2(u.x + v.x, u.y + v.y);
            cplx d = make_float2(u.x - v.x, u.y - v.y);
            A[b] = cmul(d, w);
        }
    }
    __syncthreads();
}

// DIT (Cooley-Tukey): bit-reversed input -> natural output. Use SIGN=+1 (inverse, unscaled).
template <int SIGN>
__device__ __forceinline__ void fft_dit_4096(cplx* A, int tid) {
    for (int t = 1; t <= 12; ++t) {
        const int len = 1 << t, half = 1 << (t - 1);
        __syncthreads();
        #pragma unroll
        for (int it = 0; it < 8; ++it) {
            int i = tid + (it << 8);
            int j = i & (half - 1);
            int a = ((i >> (t - 1)) << t) + j;
            int b = a + half;
            float ang = (float)(2.0 * PI_D) * (float)j / (float)len;
            float sn, cs; __sincosf(ang, &sn, &cs);
            cplx w = make_float2(cs, (float)SIGN * sn);
            cplx u = A[a];
            cplx wv = cmul(A[b], w);
            A[a] = make_float2(u.x + wv.x, u.y + wv.y);
            A[b] = make_float2(u.x - wv.x, u.y - wv.y);
        }
    }
    __syncthreads();
}

__device__ __forceinline__ float scale_fn(float x) {
    float s = 1.0f / (1.0f + expf(-x));
    return 2.0f * powf(s, 2.3025851f) + 1e-7f;   // log(10) = 2.302585093
}

// --- exclusive prefix sum of pitch per batch (fp64), 8 serial chains ---
__global__ void k_prefix(const float* __restrict__ pitch, double* __restrict__ prefix) {
    int b = threadIdx.x;
    if (b < NBATCH) {
        double s = 0.0;
        const float* p = pitch + b * NFRAME;
        double* o = prefix + b * NFRAME;
        for (int f = 0; f < NFRAME; ++f) { o[f] = s; s += (double)p[f]; }
    }
}

// --- reverb impulse: imp[0]=1; imp[t]=rn[t]*exp(-c*t)*sigmoid(wet), zero-pad to 16384 ---
__global__ void k_imp(const float* __restrict__ rn, const float* __restrict__ decay,
                      const float* __restrict__ wet, float* __restrict__ imp) {
    int t = blockIdx.x * blockDim.x + threadIdx.x;
    if (t >= IMPN) return;
    double c  = log1p(exp(-(double)decay[0])) * (500.0 / (double)SRATE); // per-sample rate
    double wg = 1.0 / (1.0 + exp(-(double)wet[0]));
    float v;
    if (t == 0)            v = 1.0f;
    else if (t < SRATE)    v = rn[t] * (float)(exp(-c * (double)t) * wg);
    else                   v = 0.0f;
    imp[t] = v;
}

// --- fused per-(b,f) frame processing + harmonic synth -> signal ---
__global__ __launch_bounds__(128) void k_synth(const float* __restrict__ amp_param,
                                               const float* __restrict__ noise_param,
                                               const float* __restrict__ pitch,
                                               const float* __restrict__ noise,
                                               const double* __restrict__ prefix,
                                               float* __restrict__ sig) {
    __shared__ float s_famps[NHARM];   // normalized amps (phase-2 input)
    __shared__ float s_amps[NHARM];    // masked raw amps
    __shared__ float s_np[NBAND];
    __shared__ float s_ct[BLK];
    __shared__ float s_ir[BLK];
    __shared__ float s_noise[BLK];
    __shared__ float s_nz[BLK];
    __shared__ float s_red[BLK];
    __shared__ float s_total;

    int bf = blockIdx.x;
    int tid = threadIdx.x;
    float pf = pitch[bf];

    if (tid < NHARM + 1) {
        float p = scale_fn(amp_param[bf * (NHARM + 1) + tid]);
        if (tid == 0) s_total = p;
        else {
            // aa = (pitch*k < sr/2) + 1e-4  -> 1.0001 or 0.0001, k = tid
            float aa = (pf * (float)tid < 8000.0f) ? 1.0001f : 0.0001f;
            s_amps[tid - 1] = p * aa;
        }
    }
    if (tid < NBAND) s_np[tid] = scale_fn(noise_param[bf * NBAND + tid] - 5.0f);
    s_ct[tid]    = (float)cos(2.0 * PI_D * (double)tid / 128.0);
    s_noise[tid] = noise[bf * BLK + tid];
    __syncthreads();

    // ir[n] = irfft(np)[n] * (0.5 + 0.5*cos(2*pi*n/128))  (roll/hann/roll collapsed)
    float irv;
    {
        int n = tid;
        float a = s_np[0];
        #pragma unroll
        for (int k = 1; k < NBAND - 1; ++k) a += 2.0f * s_np[k] * s_ct[(k * n) & 127];
        a += s_np[NBAND - 1] * s_ct[(64 * n) & 127];
        a *= (1.0f / 128.0f);
        a *= 0.5f + 0.5f * s_ct[n];
        irv = a;
    }

    // sum of masked amps (tree reduce over 128, entries >=100 are 0)
    s_red[tid] = (tid < NHARM) ? s_amps[tid] : 0.0f;
    __syncthreads();
    for (int s = 64; s > 0; s >>= 1) {
        if (tid < s) s_red[tid] += s_red[tid + s];
        __syncthreads();
    }
    if (tid < NHARM) s_famps[tid] = s_amps[tid] / s_red[0] * s_total;
    s_ir[tid] = irv;
    __syncthreads();

    // nz[p] = sum_{m<=p} noise[m] * ir[p-m]
    float nzv = 0.0f;
    for (int m = 0; m <= tid; ++m) nzv += s_noise[m] * s_ir[tid - m];
    s_nz[tid] = nzv;
    __syncthreads();

    // harmonic synth: omega[n] = 2pi/sr * (128*prefix_excl + (r+1)*pitch)
    double om = (2.0 * PI_D / (double)SRATE) *
                (128.0 * prefix[bf] + (double)(tid + 1) * (double)pf);
    float th = (float)fmod(om, 2.0 * PI_D);   // exact for integer-k harmonics
    float h = 0.0f;
    #pragma unroll 4
    for (int k = 1; k <= NHARM; ++k) h += sinf(th * (float)k) * s_famps[k - 1];
    sig[bf * BLK + tid] = h + s_nz[tid];
}

// --- FFT of impulse partitions: H[p] = DIF_FFT([imp_p(2048), zeros(2048)]) (bit-rev order) ---
__global__ __launch_bounds__(256) void k_ffth(const float* __restrict__ imp,
                                              cplx* __restrict__ H) {
    __shared__ cplx sA[FFTN];
    int p = blockIdx.x, tid = threadIdx.x;
    for (int i = tid; i < FFTN; i += 256) {
        float v = (i < HOP) ? imp[p * HOP + i] : 0.0f;
        sA[i] = make_float2(v, 0.0f);
    }
    fft_dif_4096<-1>(sA, tid);     // sync at each stage top covers the staging writes
    for (int i = tid; i < FFTN; i += 256) H[p * FFTN + i] = sA[i];
}

// --- FFT of signal frames: X[b][m] = DIF_FFT(sig[b][2048(m-1) .. 2048(m+1))) ---
__global__ __launch_bounds__(256) void k_fftsig(const float* __restrict__ sig,
                                                cplx* __restrict__ X) {
    __shared__ cplx sA[FFTN];
    int bm = blockIdx.x;
    int b = bm / NHOPS, m = bm % NHOPS;
    int tid = threadIdx.x;
    const float* sb = sig + b * NSAMP;
    int base = HOP * (m - 1);
    for (int i = tid; i < FFTN; i += 256) {
        int idx = base + i;                      // idx < NSAMP guaranteed (m<=24)
        float v = (idx >= 0) ? sb[idx] : 0.0f;
        sA[i] = make_float2(v, 0.0f);
    }
    fft_dif_4096<-1>(sA, tid);
    for (int i = tid; i < FFTN; i += 256) X[bm * FFTN + i] = sA[i];
}

// --- Y = sum_p X[b][m-p]*H[p] (bit-rev domain), IFFT(DIT), write out hop m ---
__global__ __launch_bounds__(256) void k_specmac_ifft(const cplx* __restrict__ X,
                                                      const cplx* __restrict__ H,
                                                      float* __restrict__ out) {
    __shared__ cplx sA[FFTN];
    int bm = blockIdx.x;
    int b = bm / NHOPS, m = bm % NHOPS;
    int tid = threadIdx.x;

    cplx acc[16];
    #pragma unroll
    for (int it = 0; it < 16; ++it) acc[it] = make_float2(0.0f, 0.0f);

    int pmax = (m < NPART - 1) ? m : (NPART - 1);
    for (int p = 0; p <= pmax; ++p) {
        const cplx* Xm = X + (b * NHOPS + (m - p)) * FFTN;
        const cplx* Hp = H + p * FFTN;
        #pragma unroll
        for (int it = 0; it < 16; ++it) {
            int i = tid + (it << 8);
            cplx xv = Xm[i], hv = Hp[i];
            cplx pr = cmul(xv, hv);
            acc[it].x += pr.x; acc[it].y += pr.y;
        }
    }
    #pragma unroll
    for (int it = 0; it < 16; ++it) sA[tid + (it << 8)] = acc[it];

    fft_dit_4096<1>(sA, tid);      // bit-rev in -> natural out (unscaled inverse)

    float* ob = out + b * NSAMP + m * HOP;
    const float s = 1.0f / (float)FFTN;
    #pragma unroll
    for (int it = 0; it < 8; ++it) {
        int j = tid + (it << 8);                 // [0,2048)
        ob[j] = sA[HOP + j].x * s;               // discard first half (overlap-save)
    }
}

extern "C" void kernel_launch(void* const* d_in, const int* in_sizes, int n_in,
                              void* d_out, int out_size, void* d_ws, size_t ws_size,
                              hipStream_t stream) {
    const float* amp_param   = (const float*)d_in[0];
    const float* noise_param = (const float*)d_in[1];
    const float* pitch       = (const float*)d_in[2];
    const float* noise       = (const float*)d_in[3];
    const float* rn          = (const float*)d_in[4];
    const float* decay       = (const float*)d_in[5];
    const float* wet         = (const float*)d_in[6];
    float* out = (float*)d_out;

    char* ws = (char*)d_ws;
    double* prefix = (double*)(ws + OFF_PREFIX);
    float*  sig    = (float*)(ws + OFF_SIG);
    float*  imp    = (float*)(ws + OFF_IMP);
    cplx*   H      = (cplx*)(ws + OFF_H);
    cplx*   X      = (cplx*)(ws + OFF_X);

    k_prefix<<<dim3(1), dim3(64), 0, stream>>>(pitch, prefix);
    k_imp<<<dim3(IMPN / 256), dim3(256), 0, stream>>>(rn, decay, wet, imp);
    k_synth<<<dim3(NBATCH * NFRAME), dim3(128), 0, stream>>>(amp_param, noise_param, pitch, noise, prefix, sig);
    k_ffth<<<dim3(NPART), dim3(256), 0, stream>>>(imp, H);
    k_fftsig<<<dim3(NBATCH * NHOPS), dim3(256), 0, stream>>>(sig, X);
    k_specmac_ifft<<<dim3(NBATCH * NHOPS), dim3(256), 0, stream>>>(X, H, out);
}

// Round 9
// 94.021 us; speedup vs baseline: 2.9038x; 1.4260x over previous
//
#include <hip/hip_runtime.h>
#include <math.h>

#define NBATCH 8
#define NFRAME 400
#define NHARM  100
#define NBAND  65
#define SRATE  16000
#define BLK    128
#define NSAMP  (NFRAME*BLK)      // 51200 samples per batch
#define IMPN   16384             // impulse padded to 8*2048
#define PI_D   3.14159265358979323846

// FFT convolution params: overlap-save, FFT 4096, hop 2048, 8 imp partitions
#define FFTN   4096
#define HOP    2048
#define NPART  8
#define NHOPS  (NSAMP / HOP)     // 25 per batch

// workspace layout (byte offsets, 8B aligned)
#define OFF_PREFIX 0             // double[8*400]            = 25600 B
#define OFF_SIG    25600         // float[8*51200]           = 1638400 B
#define OFF_H      1729536       // float2[8][4096]          = 262144 B
#define OFF_X      1991680       // float2[8*25][4096]       = 6553600 B
// end 8545280 (~8.5 MB)

typedef float2 cplx;

__device__ __forceinline__ cplx cmul(cplx a, cplx b) {
    return make_float2(a.x * b.x - a.y * b.y, a.x * b.y + a.y * b.x);
}

// ---- 4096-pt in-place complex FFT in LDS, 256 threads ----
// DIF (Gentleman-Sande): natural input -> bit-reversed output. Use SIGN=-1 (forward).
template <int SIGN>
__device__ __forceinline__ void fft_dif_4096(cplx* A, int tid) {
    for (int t = 12; t >= 1; --t) {
        const int len = 1 << t, half = 1 << (t - 1);
        __syncthreads();
        #pragma unroll
        for (int it = 0; it < 8; ++it) {
            int i = tid + (it << 8);               // butterfly idx [0,2048)
            int j = i & (half - 1);
            int a = ((i >> (t - 1)) << t) + j;
            int b = a + half;
            float ang = (float)(2.0 * PI_D) * (float)j / (float)len;
            float sn, cs; __sincosf(ang, &sn, &cs);
            cplx w = make_float2(cs, (float)SIGN * sn);
            cplx u = A[a], v = A[b];
            A[a] = make_float2(u.x + v.x, u.y + v.y);
            cplx d = make_float2(u.x - v.x, u.y - v.y);
            A[b] = cmul(d, w);
        }
    }
    __syncthreads();
}

// DIT (Cooley-Tukey): bit-reversed input -> natural output. Use SIGN=+1 (inverse, unscaled).
template <int SIGN>
__device__ __forceinline__ void fft_dit_4096(cplx* A, int tid) {
    for (int t = 1; t <= 12; ++t) {
        const int len = 1 << t, half = 1 << (t - 1);
        __syncthreads();
        #pragma unroll
        for (int it = 0; it < 8; ++it) {
            int i = tid + (it << 8);
            int j = i & (half - 1);
            int a = ((i >> (t - 1)) << t) + j;
            int b = a + half;
            float ang = (float)(2.0 * PI_D) * (float)j / (float)len;
            float sn, cs; __sincosf(ang, &sn, &cs);
            cplx w = make_float2(cs, (float)SIGN * sn);
            cplx u = A[a];
            cplx wv = cmul(A[b], w);
            A[a] = make_float2(u.x + wv.x, u.y + wv.y);
            A[b] = make_float2(u.x - wv.x, u.y - wv.y);
        }
    }
    __syncthreads();
}

// scale_fn via explicit exp/log (powf is ~40 inst): 2*sigmoid(x)^log(10) + 1e-7
__device__ __forceinline__ float scale_fn(float x) {
    float s = 1.0f / (1.0f + __expf(-x));
    return 2.0f * __expf(2.3025851f * __logf(s)) + 1e-7f;
}

// --- exclusive prefix sum of pitch per batch (fp64), 8 serial chains ---
__global__ void k_prefix(const float* __restrict__ pitch, double* __restrict__ prefix) {
    int b = threadIdx.x;
    if (b < NBATCH) {
        double s = 0.0;
        const float* p = pitch + b * NFRAME;
        double* o = prefix + b * NFRAME;
        for (int f = 0; f < NFRAME; ++f) { o[f] = s; s += (double)p[f]; }
    }
}

// --- fused per-(b,f) frame processing + harmonic synth -> signal ---
// Chebyshev recurrences replace sinf-per-harmonic and the cos table.
__global__ __launch_bounds__(128) void k_synth(const float* __restrict__ amp_param,
                                               const float* __restrict__ noise_param,
                                               const float* __restrict__ pitch,
                                               const float* __restrict__ noise,
                                               const double* __restrict__ prefix,
                                               float* __restrict__ sig) {
    __shared__ float s_famps[NHARM];   // normalized amps (phase-2 input)
    __shared__ float s_amps[NHARM];    // masked raw amps
    __shared__ float s_np[NBAND];
    __shared__ float s_ir[BLK];
    __shared__ float s_noise[BLK];
    __shared__ float s_nz[BLK];
    __shared__ float s_red[BLK];
    __shared__ float s_total;

    int bf = blockIdx.x;
    int tid = threadIdx.x;
    float pf = pitch[bf];

    if (tid < NHARM + 1) {
        float p = scale_fn(amp_param[bf * (NHARM + 1) + tid]);
        if (tid == 0) s_total = p;
        else {
            // aa = (pitch*k < sr/2) + 1e-4  -> 1.0001 or 0.0001, k = tid
            float aa = (pf * (float)tid < 8000.0f) ? 1.0001f : 0.0001f;
            s_amps[tid - 1] = p * aa;
        }
    }
    if (tid < NBAND) s_np[tid] = scale_fn(noise_param[bf * NBAND + tid] - 5.0f);
    s_noise[tid] = noise[bf * BLK + tid];
    __syncthreads();

    // ir[n] = (1/128) * (np[0] + 2*sum_{k=1}^{63} np[k] cos(2pi k n/128) + np[64] cos(pi n))
    //         * (0.5 + 0.5*cos(2pi n/128))       [roll/hann/roll collapsed]
    float irv;
    {
        float ang = (float)(2.0 * PI_D / 128.0) * (float)tid;
        float sn, c; __sincosf(ang, &sn, &c);
        float c2 = 2.0f * c;
        float u0 = 1.0f, u1 = c;            // u_k = cos(k*ang)
        float t = 0.0f;
        #pragma unroll
        for (int k = 1; k < 64; ++k) {
            t = fmaf(s_np[k], u1, t);
            float u2 = fmaf(c2, u1, -u0);
            u0 = u1; u1 = u2;
        }
        // after loop u1 = cos(64*ang)
        float a = fmaf(2.0f, t, s_np[0]);
        a = fmaf(s_np[64], u1, a);
        a *= (1.0f / 128.0f);
        a *= fmaf(0.5f, c, 0.5f);
        irv = a;
    }

    // sum of masked amps (tree reduce over 128, entries >=100 are 0)
    s_red[tid] = (tid < NHARM) ? s_amps[tid] : 0.0f;
    __syncthreads();
    for (int s = 64; s > 0; s >>= 1) {
        if (tid < s) s_red[tid] += s_red[tid + s];
        __syncthreads();
    }
    if (tid < NHARM) s_famps[tid] = s_amps[tid] / s_red[0] * s_total;
    s_ir[tid] = irv;
    __syncthreads();

    // nz[p] = sum_{m<=p} noise[m] * ir[p-m]
    float nzv = 0.0f;
    for (int m = 0; m <= tid; ++m) nzv = fmaf(s_noise[m], s_ir[tid - m], nzv);
    s_nz[tid] = nzv;
    __syncthreads();

    // harmonic synth: omega[n] = 2pi/sr * (128*prefix_excl + (r+1)*pitch)
    // h = sum_k sin(k*th) * famps[k-1] via sin recurrence
    double om = (2.0 * PI_D / (double)SRATE) *
                (128.0 * prefix[bf] + (double)(tid + 1) * (double)pf);
    float th = (float)fmod(om, 2.0 * PI_D);   // exact for integer-k harmonics
    float h;
    {
        float s1, cs; __sincosf(th, &s1, &cs);
        float c2 = 2.0f * cs;
        float s0 = 0.0f;                    // sin(0)
        h = 0.0f;
        #pragma unroll
        for (int k = 1; k <= NHARM; ++k) {
            h = fmaf(s1, s_famps[k - 1], h);
            float s2 = fmaf(c2, s1, -s0);
            s0 = s1; s1 = s2;
        }
    }
    sig[bf * BLK + tid] = h + s_nz[tid];
}

// --- impulse partitions (inline imp compute) -> H[p] = DIF_FFT (bit-rev order) ---
__global__ __launch_bounds__(256) void k_ffth(const float* __restrict__ rn,
                                              const float* __restrict__ decay,
                                              const float* __restrict__ wet,
                                              cplx* __restrict__ H) {
    __shared__ cplx sA[FFTN];
    int p = blockIdx.x, tid = threadIdx.x;
    double c  = log1p(exp(-(double)decay[0])) * (500.0 / (double)SRATE);
    double wg = 1.0 / (1.0 + exp(-(double)wet[0]));
    for (int i = tid; i < FFTN; i += 256) {
        float v = 0.0f;
        if (i < HOP) {
            int t = p * HOP + i;
            if (t == 0)         v = 1.0f;
            else if (t < SRATE) v = rn[t] * (float)(exp(-c * (double)t) * wg);
        }
        sA[i] = make_float2(v, 0.0f);
    }
    fft_dif_4096<-1>(sA, tid);     // sync at each stage top covers the staging writes
    for (int i = tid; i < FFTN; i += 256) H[p * FFTN + i] = sA[i];
}

// --- FFT of signal frames: X[b][m] = DIF_FFT(sig[b][2048(m-1) .. 2048(m+1))) ---
__global__ __launch_bounds__(256) void k_fftsig(const float* __restrict__ sig,
                                                cplx* __restrict__ X) {
    __shared__ cplx sA[FFTN];
    int bm = blockIdx.x;
    int b = bm / NHOPS, m = bm % NHOPS;
    int tid = threadIdx.x;
    const float* sb = sig + b * NSAMP;
    int base = HOP * (m - 1);
    for (int i = tid; i < FFTN; i += 256) {
        int idx = base + i;                      // idx < NSAMP guaranteed (m<=24)
        float v = (idx >= 0) ? sb[idx] : 0.0f;
        sA[i] = make_float2(v, 0.0f);
    }
    fft_dif_4096<-1>(sA, tid);
    for (int i = tid; i < FFTN; i += 256) X[bm * FFTN + i] = sA[i];
}

// --- Y = sum_p X[b][m-p]*H[p] (bit-rev domain), IFFT(DIT), write out hop m ---
__global__ __launch_bounds__(256) void k_specmac_ifft(const cplx* __restrict__ X,
                                                      const cplx* __restrict__ H,
                                                      float* __restrict__ out) {
    __shared__ cplx sA[FFTN];
    int bm = blockIdx.x;
    int b = bm / NHOPS, m = bm % NHOPS;
    int tid = threadIdx.x;

    cplx acc[16];
    #pragma unroll
    for (int it = 0; it < 16; ++it) acc[it] = make_float2(0.0f, 0.0f);

    int pmax = (m < NPART - 1) ? m : (NPART - 1);
    for (int p = 0; p <= pmax; ++p) {
        const cplx* Xm = X + (b * NHOPS + (m - p)) * FFTN;
        const cplx* Hp = H + p * FFTN;
        #pragma unroll
        for (int it = 0; it < 16; ++it) {
            int i = tid + (it << 8);
            cplx xv = Xm[i], hv = Hp[i];
            cplx pr = cmul(xv, hv);
            acc[it].x += pr.x; acc[it].y += pr.y;
        }
    }
    #pragma unroll
    for (int it = 0; it < 16; ++it) sA[tid + (it << 8)] = acc[it];

    fft_dit_4096<1>(sA, tid);      // bit-rev in -> natural out (unscaled inverse)

    float* ob = out + b * NSAMP + m * HOP;
    const float s = 1.0f / (float)FFTN;
    #pragma unroll
    for (int it = 0; it < 8; ++it) {
        int j = tid + (it << 8);                 // [0,2048)
        ob[j] = sA[HOP + j].x * s;               // discard first half (overlap-save)
    }
}

extern "C" void kernel_launch(void* const* d_in, const int* in_sizes, int n_in,
                              void* d_out, int out_size, void* d_ws, size_t ws_size,
                              hipStream_t stream) {
    const float* amp_param   = (const float*)d_in[0];
    const float* noise_param = (const float*)d_in[1];
    const float* pitch       = (const float*)d_in[2];
    const float* noise       = (const float*)d_in[3];
    const float* rn          = (const float*)d_in[4];
    const float* decay       = (const float*)d_in[5];
    const float* wet         = (const float*)d_in[6];
    float* out = (float*)d_out;

    char* ws = (char*)d_ws;
    double* prefix = (double*)(ws + OFF_PREFIX);
    float*  sig    = (float*)(ws + OFF_SIG);
    cplx*   H      = (cplx*)(ws + OFF_H);
    cplx*   X      = (cplx*)(ws + OFF_X);

    k_prefix<<<dim3(1), dim3(64), 0, stream>>>(pitch, prefix);
    k_ffth<<<dim3(NPART), dim3(256), 0, stream>>>(rn, decay, wet, H);
    k_synth<<<dim3(NBATCH * NFRAME), dim3(128), 0, stream>>>(amp_param, noise_param, pitch, noise, prefix, sig);
    k_fftsig<<<dim3(NBATCH * NHOPS), dim3(256), 0, stream>>>(sig, X);
    k_specmac_ifft<<<dim3(NBATCH * NHOPS), dim3(256), 0, stream>>>(X, H, out);
}

// Round 10
// 68.479 us; speedup vs baseline: 3.9868x; 1.3730x over previous
//
#include <hip/hip_runtime.h>
#include <math.h>

#define NBATCH 8
#define NFRAME 400
#define NHARM  100
#define NBAND  65
#define SRATE  16000
#define BLK    128
#define NSAMP  (NFRAME*BLK)      // 51200 samples per batch
#define PI_D   3.14159265358979323846

// FFT convolution params: overlap-save, FFT 4096, hop 2048, 8 imp partitions
#define FFTN   4096
#define HOP    2048
#define NPART  8
#define NHOPS  (NSAMP / HOP)     // 25 per batch

// workspace layout (byte offsets, 8B aligned)
#define OFF_PREFIX 0             // double[8*400]            = 25600 B
#define OFF_SIG    25600         // float[8*51200]           = 1638400 B
#define OFF_H      1729536       // float2[8][4096]          = 262144 B
#define OFF_X      1991680       // float2[8*25][4096]       = 6553600 B
// end 8545280 (~8.5 MB)

typedef float2 cplx;

__device__ __forceinline__ cplx cmul(cplx a, cplx b) {
    return make_float2(a.x * b.x - a.y * b.y, a.x * b.y + a.y * b.x);
}
// multiply by SIGN*i:  SIGN=-1: z*(-i) = (z.y, -z.x);  SIGN=+1: z*(+i) = (-z.y, z.x)
template <int SIGN>
__device__ __forceinline__ cplx rot90(cplx z) {
    return (SIGN < 0) ? make_float2(z.y, -z.x) : make_float2(-z.y, z.x);
}

// ---- 4096-pt in-place complex FFT in LDS, 256 threads, fused radix-2^2 ----
// Two radix-2 stages (t, t-1) per LDS pass. Group {a, a+Q, a+h, a+h+Q},
// Q=2^(t-2), h=2Q, j = g&(Q-1), a = ((g>>(t-2))<<t)+j.
// Twiddles: w1 = W_L^j, stage-t pair2 twiddle = w1*(SIGN*i) [Q=L/4], w3 = w1^2.
// DIF (Gentleman-Sande): natural in -> digit-reversed out. SIGN=-1 forward.
template <int SIGN>
__device__ __forceinline__ void fft_dif_4096(cplx* A, int tid) {
    #pragma unroll
    for (int t = 12; t >= 2; t -= 2) {
        const int Q = 1 << (t - 2), h = 1 << (t - 1);
        __syncthreads();
        #pragma unroll
        for (int it = 0; it < 4; ++it) {
            int g = tid + (it << 8);               // group idx [0,1024)
            int j = g & (Q - 1);
            int a = ((g >> (t - 2)) << t) + j;
            cplx x0 = A[a], x1 = A[a + Q], x2 = A[a + h], x3 = A[a + h + Q];
            float ang = (float)(2.0 * PI_D) * (float)j / (float)(1 << t);
            float sn, cs; __sincosf(ang, &sn, &cs);
            cplx w1 = make_float2(cs, (float)SIGN * sn);
            cplx w3 = make_float2(cs * cs - sn * sn, 2.0f * cs * sn * (float)SIGN);
            // stage t
            cplx p0 = make_float2(x0.x + x2.x, x0.y + x2.y);
            cplx p2 = cmul(make_float2(x0.x - x2.x, x0.y - x2.y), w1);
            cplx p1 = make_float2(x1.x + x3.x, x1.y + x3.y);
            cplx p3 = rot90<SIGN>(cmul(make_float2(x1.x - x3.x, x1.y - x3.y), w1));
            // stage t-1
            A[a]         = make_float2(p0.x + p1.x, p0.y + p1.y);
            A[a + Q]     = cmul(make_float2(p0.x - p1.x, p0.y - p1.y), w3);
            A[a + h]     = make_float2(p2.x + p3.x, p2.y + p3.y);
            A[a + h + Q] = cmul(make_float2(p2.x - p3.x, p2.y - p3.y), w3);
        }
    }
    __syncthreads();
}

// DIT (Cooley-Tukey): digit-reversed in -> natural out. SIGN=+1 inverse (unscaled).
// Exact stage-pair inverse of fft_dif_4096 (verified algebraically: recovers 4x inputs).
template <int SIGN>
__device__ __forceinline__ void fft_dit_4096(cplx* A, int tid) {
    #pragma unroll
    for (int t = 2; t <= 12; t += 2) {
        const int Q = 1 << (t - 2), h = 1 << (t - 1);
        __syncthreads();
        #pragma unroll
        for (int it = 0; it < 4; ++it) {
            int g = tid + (it << 8);
            int j = g & (Q - 1);
            int a = ((g >> (t - 2)) << t) + j;
            cplx x0 = A[a], x1 = A[a + Q], x2 = A[a + h], x3 = A[a + h + Q];
            float ang = (float)(2.0 * PI_D) * (float)j / (float)(1 << t);
            float sn, cs; __sincosf(ang, &sn, &cs);
            cplx w1 = make_float2(cs, (float)SIGN * sn);
            cplx w3 = make_float2(cs * cs - sn * sn, 2.0f * cs * sn * (float)SIGN);
            // stage t-1
            cplx b1 = cmul(x1, w3);
            cplx q0 = make_float2(x0.x + b1.x, x0.y + b1.y);
            cplx q1 = make_float2(x0.x - b1.x, x0.y - b1.y);
            cplx b3 = cmul(x3, w3);
            cplx q2 = make_float2(x2.x + b3.x, x2.y + b3.y);
            cplx q3 = make_float2(x2.x - b3.x, x2.y - b3.y);
            // stage t
            cplx c2 = cmul(q2, w1);
            cplx c3 = rot90<SIGN>(cmul(q3, w1));
            A[a]         = make_float2(q0.x + c2.x, q0.y + c2.y);
            A[a + h]     = make_float2(q0.x - c2.x, q0.y - c2.y);
            A[a + Q]     = make_float2(q1.x + c3.x, q1.y + c3.y);
            A[a + h + Q] = make_float2(q1.x - c3.x, q1.y - c3.y);
        }
    }
    __syncthreads();
}

// scale_fn via explicit exp/log (powf is ~40 inst): 2*sigmoid(x)^log(10) + 1e-7
__device__ __forceinline__ float scale_fn(float x) {
    float s = 1.0f / (1.0f + __expf(-x));
    return 2.0f * __expf(2.3025851f * __logf(s)) + 1e-7f;
}

// --- fused: impulse partitions -> H[p] (blocks 0..7)  +  pitch prefix (block 8) ---
__global__ __launch_bounds__(256) void k_ffth(const float* __restrict__ rn,
                                              const float* __restrict__ decay,
                                              const float* __restrict__ wet,
                                              const float* __restrict__ pitch,
                                              cplx* __restrict__ H,
                                              double* __restrict__ prefix) {
    __shared__ cplx sA[FFTN];
    int tid = threadIdx.x;
    if (blockIdx.x == NPART) {
        // exclusive prefix sum of pitch per batch (fp64), 8 serial chains
        if (tid < NBATCH) {
            double s = 0.0;
            const float* p = pitch + tid * NFRAME;
            double* o = prefix + tid * NFRAME;
            for (int f = 0; f < NFRAME; ++f) { o[f] = s; s += (double)p[f]; }
        }
        return;
    }
    int p = blockIdx.x;
    double c  = log1p(exp(-(double)decay[0])) * (500.0 / (double)SRATE);
    double wg = 1.0 / (1.0 + exp(-(double)wet[0]));
    for (int i = tid; i < FFTN; i += 256) {
        float v = 0.0f;
        if (i < HOP) {
            int t = p * HOP + i;
            if (t == 0)         v = 1.0f;
            else if (t < SRATE) v = rn[t] * (float)(exp(-c * (double)t) * wg);
        }
        sA[i] = make_float2(v, 0.0f);
    }
    fft_dif_4096<-1>(sA, tid);     // sync at each stage top covers the staging writes
    for (int i = tid; i < FFTN; i += 256) H[p * FFTN + i] = sA[i];
}

// --- fused per-(b,f) frame processing + harmonic synth -> signal ---
__global__ __launch_bounds__(128) void k_synth(const float* __restrict__ amp_param,
                                               const float* __restrict__ noise_param,
                                               const float* __restrict__ pitch,
                                               const float* __restrict__ noise,
                                               const double* __restrict__ prefix,
                                               float* __restrict__ sig) {
    __shared__ float s_famps[NHARM];   // normalized amps (phase-2 input)
    __shared__ float s_amps[NHARM];    // masked raw amps
    __shared__ float s_np[NBAND];
    __shared__ float s_ir[BLK];
    __shared__ float s_noise[BLK];
    __shared__ float s_red[BLK];       // reduction temps, then nz partials
    __shared__ float s_total;

    int bf = blockIdx.x;
    int tid = threadIdx.x;
    float pf = pitch[bf];

    if (tid < NHARM + 1) {
        float p = scale_fn(amp_param[bf * (NHARM + 1) + tid]);
        if (tid == 0) s_total = p;
        else {
            // aa = (pitch*k < sr/2) + 1e-4  -> 1.0001 or 0.0001, k = tid
            float aa = (pf * (float)tid < 8000.0f) ? 1.0001f : 0.0001f;
            s_amps[tid - 1] = p * aa;
        }
    }
    if (tid < NBAND) s_np[tid] = scale_fn(noise_param[bf * NBAND + tid] - 5.0f);
    s_noise[tid] = noise[bf * BLK + tid];
    __syncthreads();

    // ir[n] = (1/128) * (np[0] + 2*sum_{k=1}^{63} np[k] cos(2pi k n/128) + np[64] cos(pi n))
    //         * (0.5 + 0.5*cos(2pi n/128))       [roll/hann/roll collapsed]
    float irv;
    {
        float ang = (float)(2.0 * PI_D / 128.0) * (float)tid;
        float sn, c; __sincosf(ang, &sn, &c);
        float c2 = 2.0f * c;
        float u0 = 1.0f, u1 = c;            // u_k = cos(k*ang)
        float t = 0.0f;
        #pragma unroll
        for (int k = 1; k < 64; ++k) {
            t = fmaf(s_np[k], u1, t);
            float u2 = fmaf(c2, u1, -u0);
            u0 = u1; u1 = u2;
        }
        // after loop u1 = cos(64*ang)
        float a = fmaf(2.0f, t, s_np[0]);
        a = fmaf(s_np[64], u1, a);
        a *= (1.0f / 128.0f);
        a *= fmaf(0.5f, c, 0.5f);
        irv = a;
    }

    // sum of masked amps (tree reduce over 128, entries >=100 are 0)
    s_red[tid] = (tid < NHARM) ? s_amps[tid] : 0.0f;
    __syncthreads();
    for (int s = 64; s > 0; s >>= 1) {
        if (tid < s) s_red[tid] += s_red[tid + s];
        __syncthreads();
    }
    float inv_red = s_red[0];
    __syncthreads();                   // s_red reads done; reuse as nz partials
    if (tid < NHARM) s_famps[tid] = s_amps[tid] / inv_red * s_total;
    s_ir[tid] = irv;
    __syncthreads();

    // nz[p] = sum_{m<=p} noise[m] * ir[p-m], balanced split:
    // thread t: lower half of output t  +  upper half of output 127-t
    float accA = 0.0f;
    {
        int p1 = tid, h1 = (p1 + 2) >> 1;          // ceil((p1+1)/2)
        for (int m = 0; m < h1; ++m) accA = fmaf(s_noise[m], s_ir[p1 - m], accA);
    }
    {
        int p2 = 127 - tid, h2 = (p2 + 2) >> 1;
        float accB = 0.0f;
        for (int m = h2; m <= p2; ++m) accB = fmaf(s_noise[m], s_ir[p2 - m], accB);
        s_red[p2] = accB;
    }
    __syncthreads();
    float nzv = accA + s_red[tid];

    // harmonic synth: omega[n] = 2pi/sr * (128*prefix_excl + (r+1)*pitch)
    // h = sum_k sin(k*th) * famps[k-1] via sin recurrence
    double om = (2.0 * PI_D / (double)SRATE) *
                (128.0 * prefix[bf] + (double)(tid + 1) * (double)pf);
    float th = (float)fmod(om, 2.0 * PI_D);   // exact for integer-k harmonics
    float h;
    {
        float s1, cs; __sincosf(th, &s1, &cs);
        float c2 = 2.0f * cs;
        float s0 = 0.0f;                    // sin(0)
        h = 0.0f;
        #pragma unroll
        for (int k = 1; k <= NHARM; ++k) {
            h = fmaf(s1, s_famps[k - 1], h);
            float s2 = fmaf(c2, s1, -s0);
            s0 = s1; s1 = s2;
        }
    }
    sig[bf * BLK + tid] = h + nzv;
}

// --- FFT of signal frames: X[b][m] = DIF_FFT(sig[b][2048(m-1) .. 2048(m+1))) ---
__global__ __launch_bounds__(256) void k_fftsig(const float* __restrict__ sig,
                                                cplx* __restrict__ X) {
    __shared__ cplx sA[FFTN];
    int bm = blockIdx.x;
    int b = bm / NHOPS, m = bm % NHOPS;
    int tid = threadIdx.x;
    const float* sb = sig + b * NSAMP;
    int base = HOP * (m - 1);
    for (int i = tid; i < FFTN; i += 256) {
        int idx = base + i;                      // idx < NSAMP guaranteed (m<=24)
        float v = (idx >= 0) ? sb[idx] : 0.0f;
        sA[i] = make_float2(v, 0.0f);
    }
    fft_dif_4096<-1>(sA, tid);
    for (int i = tid; i < FFTN; i += 256) X[bm * FFTN + i] = sA[i];
}

// --- Y = sum_p X[b][m-p]*H[p] (digit-rev domain), IFFT(DIT), write out hop m ---
__global__ __launch_bounds__(256) void k_specmac_ifft(const cplx* __restrict__ X,
                                                      const cplx* __restrict__ H,
                                                      float* __restrict__ out) {
    __shared__ cplx sA[FFTN];
    int bm = blockIdx.x;
    int b = bm / NHOPS, m = bm % NHOPS;
    int tid = threadIdx.x;

    cplx acc[16];
    #pragma unroll
    for (int it = 0; it < 16; ++it) acc[it] = make_float2(0.0f, 0.0f);

    int pmax = (m < NPART - 1) ? m : (NPART - 1);
    for (int p = 0; p <= pmax; ++p) {
        const cplx* Xm = X + (b * NHOPS + (m - p)) * FFTN;
        const cplx* Hp = H + p * FFTN;
        #pragma unroll
        for (int it = 0; it < 16; ++it) {
            int i = tid + (it << 8);
            cplx xv = Xm[i], hv = Hp[i];
            cplx pr = cmul(xv, hv);
            acc[it].x += pr.x; acc[it].y += pr.y;
        }
    }
    #pragma unroll
    for (int it = 0; it < 16; ++it) sA[tid + (it << 8)] = acc[it];

    fft_dit_4096<1>(sA, tid);      // digit-rev in -> natural out (unscaled inverse)

    float* ob = out + b * NSAMP + m * HOP;
    const float s = 1.0f / (float)FFTN;
    #pragma unroll
    for (int it = 0; it < 8; ++it) {
        int j = tid + (it << 8);                 // [0,2048)
        ob[j] = sA[HOP + j].x * s;               // discard first half (overlap-save)
    }
}

extern "C" void kernel_launch(void* const* d_in, const int* in_sizes, int n_in,
                              void* d_out, int out_size, void* d_ws, size_t ws_size,
                              hipStream_t stream) {
    const float* amp_param   = (const float*)d_in[0];
    const float* noise_param = (const float*)d_in[1];
    const float* pitch       = (const float*)d_in[2];
    const float* noise       = (const float*)d_in[3];
    const float* rn          = (const float*)d_in[4];
    const float* decay       = (const float*)d_in[5];
    const float* wet         = (const float*)d_in[6];
    float* out = (float*)d_out;

    char* ws = (char*)d_ws;
    double* prefix = (double*)(ws + OFF_PREFIX);
    float*  sig    = (float*)(ws + OFF_SIG);
    cplx*   H      = (cplx*)(ws + OFF_H);
    cplx*   X      = (cplx*)(ws + OFF_X);

    k_ffth<<<dim3(NPART + 1), dim3(256), 0, stream>>>(rn, decay, wet, pitch, H, prefix);
    k_synth<<<dim3(NBATCH * NFRAME), dim3(128), 0, stream>>>(amp_param, noise_param, pitch, noise, prefix, sig);
    k_fftsig<<<dim3(NBATCH * NHOPS), dim3(256), 0, stream>>>(sig, X);
    k_specmac_ifft<<<dim3(NBATCH * NHOPS), dim3(256), 0, stream>>>(X, H, out);
}

// Round 11
// 66.528 us; speedup vs baseline: 4.1038x; 1.0293x over previous
//
#include <hip/hip_runtime.h>
#include <math.h>

#define NBATCH 8
#define NFRAME 400
#define NHARM  100
#define NBAND  65
#define SRATE  16000
#define BLK    128
#define NSAMP  (NFRAME*BLK)      // 51200 samples per batch
#define PI_D   3.14159265358979323846

// FFT convolution params: overlap-save, FFT 4096, hop 2048, 8 imp partitions.
// Two real batches packed per complex FFT (imp real => conv is complex-linear).
#define FFTN   4096
#define HOP    2048
#define NPART  8
#define NHOPS  (NSAMP / HOP)     // 25 per batch
#define NPAIR  (NBATCH / 2)      // 4 batch-pairs

// workspace layout (byte offsets, 8B aligned)
#define OFF_PREFIX 0             // double[8*400]            = 25600 B
#define OFF_SIG    25600         // float[8*51200]           = 1638400 B
#define OFF_H      1729536       // float2[8][4096]          = 262144 B
#define OFF_X      1991680       // float2[4*25][4096]       = 3276800 B
// end 5268480 (~5.3 MB)

typedef float2 cplx;

__device__ __forceinline__ cplx cmul(cplx a, cplx b) {
    return make_float2(a.x * b.x - a.y * b.y, a.x * b.y + a.y * b.x);
}
// multiply by SIGN*i:  SIGN=-1: z*(-i) = (z.y, -z.x);  SIGN=+1: z*(+i) = (-z.y, z.x)
template <int SIGN>
__device__ __forceinline__ cplx rot90(cplx z) {
    return (SIGN < 0) ? make_float2(z.y, -z.x) : make_float2(-z.y, z.x);
}

// ---- 4096-pt in-place complex FFT in LDS, 256 threads, fused radix-2^2 ----
// DIF (Gentleman-Sande): natural in -> digit-reversed out. SIGN=-1 forward.
template <int SIGN>
__device__ __forceinline__ void fft_dif_4096(cplx* A, int tid) {
    #pragma unroll
    for (int t = 12; t >= 2; t -= 2) {
        const int Q = 1 << (t - 2), h = 1 << (t - 1);
        __syncthreads();
        #pragma unroll
        for (int it = 0; it < 4; ++it) {
            int g = tid + (it << 8);               // group idx [0,1024)
            int j = g & (Q - 1);
            int a = ((g >> (t - 2)) << t) + j;
            cplx x0 = A[a], x1 = A[a + Q], x2 = A[a + h], x3 = A[a + h + Q];
            float ang = (float)(2.0 * PI_D) * (float)j / (float)(1 << t);
            float sn, cs; __sincosf(ang, &sn, &cs);
            cplx w1 = make_float2(cs, (float)SIGN * sn);
            cplx w3 = make_float2(cs * cs - sn * sn, 2.0f * cs * sn * (float)SIGN);
            // stage t
            cplx p0 = make_float2(x0.x + x2.x, x0.y + x2.y);
            cplx p2 = cmul(make_float2(x0.x - x2.x, x0.y - x2.y), w1);
            cplx p1 = make_float2(x1.x + x3.x, x1.y + x3.y);
            cplx p3 = rot90<SIGN>(cmul(make_float2(x1.x - x3.x, x1.y - x3.y), w1));
            // stage t-1
            A[a]         = make_float2(p0.x + p1.x, p0.y + p1.y);
            A[a + Q]     = cmul(make_float2(p0.x - p1.x, p0.y - p1.y), w3);
            A[a + h]     = make_float2(p2.x + p3.x, p2.y + p3.y);
            A[a + h + Q] = cmul(make_float2(p2.x - p3.x, p2.y - p3.y), w3);
        }
    }
    __syncthreads();
}

// DIT (Cooley-Tukey): digit-reversed in -> natural out. SIGN=+1 inverse (unscaled).
template <int SIGN>
__device__ __forceinline__ void fft_dit_4096(cplx* A, int tid) {
    #pragma unroll
    for (int t = 2; t <= 12; t += 2) {
        const int Q = 1 << (t - 2), h = 1 << (t - 1);
        __syncthreads();
        #pragma unroll
        for (int it = 0; it < 4; ++it) {
            int g = tid + (it << 8);
            int j = g & (Q - 1);
            int a = ((g >> (t - 2)) << t) + j;
            cplx x0 = A[a], x1 = A[a + Q], x2 = A[a + h], x3 = A[a + h + Q];
            float ang = (float)(2.0 * PI_D) * (float)j / (float)(1 << t);
            float sn, cs; __sincosf(ang, &sn, &cs);
            cplx w1 = make_float2(cs, (float)SIGN * sn);
            cplx w3 = make_float2(cs * cs - sn * sn, 2.0f * cs * sn * (float)SIGN);
            // stage t-1
            cplx b1 = cmul(x1, w3);
            cplx q0 = make_float2(x0.x + b1.x, x0.y + b1.y);
            cplx q1 = make_float2(x0.x - b1.x, x0.y - b1.y);
            cplx b3 = cmul(x3, w3);
            cplx q2 = make_float2(x2.x + b3.x, x2.y + b3.y);
            cplx q3 = make_float2(x2.x - b3.x, x2.y - b3.y);
            // stage t
            cplx c2 = cmul(q2, w1);
            cplx c3 = rot90<SIGN>(cmul(q3, w1));
            A[a]         = make_float2(q0.x + c2.x, q0.y + c2.y);
            A[a + h]     = make_float2(q0.x - c2.x, q0.y - c2.y);
            A[a + Q]     = make_float2(q1.x + c3.x, q1.y + c3.y);
            A[a + h + Q] = make_float2(q1.x - c3.x, q1.y - c3.y);
        }
    }
    __syncthreads();
}

// scale_fn via explicit exp/log (powf is ~40 inst): 2*sigmoid(x)^log(10) + 1e-7
__device__ __forceinline__ float scale_fn(float x) {
    float s = 1.0f / (1.0f + __expf(-x));
    return 2.0f * __expf(2.3025851f * __logf(s)) + 1e-7f;
}

// --- fused: impulse partitions -> H[p] (blocks 0..7, scaled by 1/FFTN)
//            + pitch prefix (block 8) ---
__global__ __launch_bounds__(256) void k_ffth(const float* __restrict__ rn,
                                              const float* __restrict__ decay,
                                              const float* __restrict__ wet,
                                              const float* __restrict__ pitch,
                                              cplx* __restrict__ H,
                                              double* __restrict__ prefix) {
    __shared__ cplx sA[FFTN];
    int tid = threadIdx.x;
    if (blockIdx.x == NPART) {
        // exclusive prefix sum of pitch per batch (fp64), 8 serial chains
        if (tid < NBATCH) {
            double s = 0.0;
            const float* p = pitch + tid * NFRAME;
            double* o = prefix + tid * NFRAME;
            for (int f = 0; f < NFRAME; ++f) { o[f] = s; s += (double)p[f]; }
        }
        return;
    }
    int p = blockIdx.x;
    double c  = log1p(exp(-(double)decay[0])) * (500.0 / (double)SRATE);
    double wg = 1.0 / (1.0 + exp(-(double)wet[0]));
    for (int i = tid; i < FFTN; i += 256) {
        float v = 0.0f;
        if (i < HOP) {
            int t = p * HOP + i;
            if (t == 0)         v = 1.0f;
            else if (t < SRATE) v = rn[t] * (float)(exp(-c * (double)t) * wg);
        }
        sA[i] = make_float2(v, 0.0f);
    }
    fft_dif_4096<-1>(sA, tid);     // sync at each stage top covers the staging writes
    const float s = 1.0f / (float)FFTN;     // fold IFFT scale into H
    for (int i = tid; i < FFTN; i += 256) {
        cplx v = sA[i];
        H[p * FFTN + i] = make_float2(v.x * s, v.y * s);
    }
}

// --- fused per-(b,f) frame processing + harmonic synth -> signal ---
__global__ __launch_bounds__(128) void k_synth(const float* __restrict__ amp_param,
                                               const float* __restrict__ noise_param,
                                               const float* __restrict__ pitch,
                                               const float* __restrict__ noise,
                                               const double* __restrict__ prefix,
                                               float* __restrict__ sig) {
    __shared__ float s_famps[NHARM];   // normalized amps (phase-2 input)
    __shared__ float s_amps[NHARM];    // masked raw amps
    __shared__ float s_np[NBAND];
    __shared__ float s_ir[BLK];
    __shared__ float s_noise[BLK];
    __shared__ float s_red[BLK];       // reduction temps, then nz partials
    __shared__ float s_total;

    int bf = blockIdx.x;
    int tid = threadIdx.x;
    float pf = pitch[bf];

    if (tid < NHARM + 1) {
        float p = scale_fn(amp_param[bf * (NHARM + 1) + tid]);
        if (tid == 0) s_total = p;
        else {
            // aa = (pitch*k < sr/2) + 1e-4  -> 1.0001 or 0.0001, k = tid
            float aa = (pf * (float)tid < 8000.0f) ? 1.0001f : 0.0001f;
            s_amps[tid - 1] = p * aa;
        }
    }
    if (tid < NBAND) s_np[tid] = scale_fn(noise_param[bf * NBAND + tid] - 5.0f);
    s_noise[tid] = noise[bf * BLK + tid];
    __syncthreads();

    // ir[n] = (1/128) * (np[0] + 2*sum_{k=1}^{63} np[k] cos(2pi k n/128) + np[64] cos(pi n))
    //         * (0.5 + 0.5*cos(2pi n/128))       [roll/hann/roll collapsed]
    float irv;
    {
        float ang = (float)(2.0 * PI_D / 128.0) * (float)tid;
        float sn, c; __sincosf(ang, &sn, &c);
        float c2 = 2.0f * c;
        float u0 = 1.0f, u1 = c;            // u_k = cos(k*ang)
        float t = 0.0f;
        #pragma unroll
        for (int k = 1; k < 64; ++k) {
            t = fmaf(s_np[k], u1, t);
            float u2 = fmaf(c2, u1, -u0);
            u0 = u1; u1 = u2;
        }
        // after loop u1 = cos(64*ang)
        float a = fmaf(2.0f, t, s_np[0]);
        a = fmaf(s_np[64], u1, a);
        a *= (1.0f / 128.0f);
        a *= fmaf(0.5f, c, 0.5f);
        irv = a;
    }

    // sum of masked amps (tree reduce over 128, entries >=100 are 0)
    s_red[tid] = (tid < NHARM) ? s_amps[tid] : 0.0f;
    __syncthreads();
    for (int s = 64; s > 0; s >>= 1) {
        if (tid < s) s_red[tid] += s_red[tid + s];
        __syncthreads();
    }
    float inv_red = s_red[0];
    __syncthreads();                   // s_red reads done; reuse as nz partials
    if (tid < NHARM) s_famps[tid] = s_amps[tid] / inv_red * s_total;
    s_ir[tid] = irv;
    __syncthreads();

    // nz[p] = sum_{m<=p} noise[m] * ir[p-m], balanced split:
    // thread t: lower half of output t  +  upper half of output 127-t
    float accA = 0.0f;
    {
        int p1 = tid, h1 = (p1 + 2) >> 1;          // ceil((p1+1)/2)
        for (int m = 0; m < h1; ++m) accA = fmaf(s_noise[m], s_ir[p1 - m], accA);
    }
    {
        int p2 = 127 - tid, h2 = (p2 + 2) >> 1;
        float accB = 0.0f;
        for (int m = h2; m <= p2; ++m) accB = fmaf(s_noise[m], s_ir[p2 - m], accB);
        s_red[p2] = accB;
    }
    __syncthreads();
    float nzv = accA + s_red[tid];

    // harmonic synth: omega[n]/2pi = (128*prefix_excl + (r+1)*pitch)/sr; th = 2pi*frac
    double q = (128.0 * prefix[bf] + (double)(tid + 1) * (double)pf) * (1.0 / 16000.0);
    float th = (float)(q - floor(q)) * (float)(2.0 * PI_D);  // exact for integer-k harmonics
    float h;
    {
        float s1, cs; __sincosf(th, &s1, &cs);
        float c2 = 2.0f * cs;
        float s0 = 0.0f;                    // sin(0)
        h = 0.0f;
        #pragma unroll
        for (int k = 1; k <= NHARM; ++k) {
            h = fmaf(s1, s_famps[k - 1], h);
            float s2 = fmaf(c2, s1, -s0);
            s0 = s1; s1 = s2;
        }
    }
    sig[bf * BLK + tid] = h + nzv;
}

// --- FFT of packed signal frames: X[pb][m] = DIF_FFT(sigA + i*sigB over hop window) ---
__global__ __launch_bounds__(256) void k_fftsig(const float* __restrict__ sig,
                                                cplx* __restrict__ X) {
    __shared__ cplx sA[FFTN];
    int bm = blockIdx.x;
    int pb = bm / NHOPS, m = bm % NHOPS;
    int tid = threadIdx.x;
    const float* sa = sig + (2 * pb) * NSAMP;
    const float* sb = sa + NSAMP;
    int base = HOP * (m - 1);
    for (int i = tid; i < FFTN; i += 256) {
        int idx = base + i;                      // idx < NSAMP guaranteed (m<=24)
        float va = 0.0f, vb = 0.0f;
        if (idx >= 0) { va = sa[idx]; vb = sb[idx]; }
        sA[i] = make_float2(va, vb);
    }
    fft_dif_4096<-1>(sA, tid);
    for (int i = tid; i < FFTN; i += 256) X[bm * FFTN + i] = sA[i];
}

// --- Y = sum_p X[pb][m-p]*H[p] (digit-rev), IFFT, Re->batch 2pb, Im->batch 2pb+1 ---
__global__ __launch_bounds__(256) void k_specmac_ifft(const cplx* __restrict__ X,
                                                      const cplx* __restrict__ H,
                                                      float* __restrict__ out) {
    __shared__ cplx sA[FFTN];
    int bm = blockIdx.x;
    int pb = bm / NHOPS, m = bm % NHOPS;
    int tid = threadIdx.x;

    cplx acc[16];
    #pragma unroll
    for (int it = 0; it < 16; ++it) acc[it] = make_float2(0.0f, 0.0f);

    int pmax = (m < NPART - 1) ? m : (NPART - 1);
    for (int p = 0; p <= pmax; ++p) {
        const cplx* Xm = X + (pb * NHOPS + (m - p)) * FFTN;
        const cplx* Hp = H + p * FFTN;
        #pragma unroll
        for (int it = 0; it < 16; ++it) {
            int i = tid + (it << 8);
            cplx xv = Xm[i], hv = Hp[i];
            cplx pr = cmul(xv, hv);
            acc[it].x += pr.x; acc[it].y += pr.y;
        }
    }
    #pragma unroll
    for (int it = 0; it < 16; ++it) sA[tid + (it << 8)] = acc[it];

    fft_dit_4096<1>(sA, tid);      // digit-rev in -> natural out (scale folded into H)

    float* ob0 = out + (2 * pb) * NSAMP + m * HOP;
    float* ob1 = ob0 + NSAMP;
    #pragma unroll
    for (int it = 0; it < 8; ++it) {
        int j = tid + (it << 8);                 // [0,2048)
        cplx v = sA[HOP + j];                    // discard first half (overlap-save)
        ob0[j] = v.x;
        ob1[j] = v.y;
    }
}

extern "C" void kernel_launch(void* const* d_in, const int* in_sizes, int n_in,
                              void* d_out, int out_size, void* d_ws, size_t ws_size,
                              hipStream_t stream) {
    const float* amp_param   = (const float*)d_in[0];
    const float* noise_param = (const float*)d_in[1];
    const float* pitch       = (const float*)d_in[2];
    const float* noise       = (const float*)d_in[3];
    const float* rn          = (const float*)d_in[4];
    const float* decay       = (const float*)d_in[5];
    const float* wet         = (const float*)d_in[6];
    float* out = (float*)d_out;

    char* ws = (char*)d_ws;
    double* prefix = (double*)(ws + OFF_PREFIX);
    float*  sig    = (float*)(ws + OFF_SIG);
    cplx*   H      = (cplx*)(ws + OFF_H);
    cplx*   X      = (cplx*)(ws + OFF_X);

    k_ffth<<<dim3(NPART + 1), dim3(256), 0, stream>>>(rn, decay, wet, pitch, H, prefix);
    k_synth<<<dim3(NBATCH * NFRAME), dim3(128), 0, stream>>>(amp_param, noise_param, pitch, noise, prefix, sig);
    k_fftsig<<<dim3(NPAIR * NHOPS), dim3(256), 0, stream>>>(sig, X);
    k_specmac_ifft<<<dim3(NPAIR * NHOPS), dim3(256), 0, stream>>>(X, H, out);
}

// Round 12
// 53.319 us; speedup vs baseline: 5.1204x; 1.2477x over previous
//
#include <hip/hip_runtime.h>
#include <math.h>

#define NBATCH 8
#define NFRAME 400
#define NHARM  100
#define NBAND  65
#define SRATE  16000
#define BLK    128
#define NSAMP  (NFRAME*BLK)      // 51200 samples per batch
#define PI_D   3.14159265358979323846

// FFT convolution params: overlap-save, FFT 4096, hop 2048, 8 imp partitions.
// Two real batches packed per complex FFT (imp real => conv is complex-linear).
#define FFTN   4096
#define HOP    2048
#define NPART  8
#define NHOPS  (NSAMP / HOP)     // 25 per batch
#define NPAIR  (NBATCH / 2)      // 4 batch-pairs
#define FTH    512               // threads per FFT block (latency-bound: short critical path)

// workspace layout (byte offsets, 8B aligned)
#define OFF_PREFIX 0             // double[8*400]            = 25600 B
#define OFF_SIG    25600         // float[8*51200]           = 1638400 B
#define OFF_H      1729536       // float2[8][4096]          = 262144 B
#define OFF_X      1991680       // float2[4*25][4096]       = 3276800 B
// end 5268480 (~5.3 MB)

typedef float2 cplx;

__device__ __forceinline__ cplx cmul(cplx a, cplx b) {
    return make_float2(a.x * b.x - a.y * b.y, a.x * b.y + a.y * b.x);
}
// multiply by SIGN*i:  SIGN=-1: z*(-i) = (z.y, -z.x);  SIGN=+1: z*(+i) = (-z.y, z.x)
template <int SIGN>
__device__ __forceinline__ cplx rot90(cplx z) {
    return (SIGN < 0) ? make_float2(z.y, -z.x) : make_float2(-z.y, z.x);
}

// ---- 4096-pt in-place complex FFT in LDS, FTH=512 threads, fused radix-2^2 ----
// DIF (Gentleman-Sande): natural in -> digit-reversed out. SIGN=-1 forward.
template <int SIGN>
__device__ __forceinline__ void fft_dif_4096(cplx* A, int tid) {
    #pragma unroll
    for (int t = 12; t >= 2; t -= 2) {
        const int Q = 1 << (t - 2), h = 1 << (t - 1);
        __syncthreads();
        #pragma unroll
        for (int it = 0; it < 2; ++it) {
            int g = tid + (it << 9);               // group idx [0,1024)
            int j = g & (Q - 1);
            int a = ((g >> (t - 2)) << t) + j;
            cplx x0 = A[a], x1 = A[a + Q], x2 = A[a + h], x3 = A[a + h + Q];
            float ang = (float)(2.0 * PI_D) * (float)j / (float)(1 << t);
            float sn, cs; __sincosf(ang, &sn, &cs);
            cplx w1 = make_float2(cs, (float)SIGN * sn);
            cplx w3 = make_float2(cs * cs - sn * sn, 2.0f * cs * sn * (float)SIGN);
            // stage t
            cplx p0 = make_float2(x0.x + x2.x, x0.y + x2.y);
            cplx p2 = cmul(make_float2(x0.x - x2.x, x0.y - x2.y), w1);
            cplx p1 = make_float2(x1.x + x3.x, x1.y + x3.y);
            cplx p3 = rot90<SIGN>(cmul(make_float2(x1.x - x3.x, x1.y - x3.y), w1));
            // stage t-1
            A[a]         = make_float2(p0.x + p1.x, p0.y + p1.y);
            A[a + Q]     = cmul(make_float2(p0.x - p1.x, p0.y - p1.y), w3);
            A[a + h]     = make_float2(p2.x + p3.x, p2.y + p3.y);
            A[a + h + Q] = cmul(make_float2(p2.x - p3.x, p2.y - p3.y), w3);
        }
    }
    __syncthreads();
}

// DIT (Cooley-Tukey): digit-reversed in -> natural out. SIGN=+1 inverse (unscaled).
template <int SIGN>
__device__ __forceinline__ void fft_dit_4096(cplx* A, int tid) {
    #pragma unroll
    for (int t = 2; t <= 12; t += 2) {
        const int Q = 1 << (t - 2), h = 1 << (t - 1);
        __syncthreads();
        #pragma unroll
        for (int it = 0; it < 2; ++it) {
            int g = tid + (it << 9);
            int j = g & (Q - 1);
            int a = ((g >> (t - 2)) << t) + j;
            cplx x0 = A[a], x1 = A[a + Q], x2 = A[a + h], x3 = A[a + h + Q];
            float ang = (float)(2.0 * PI_D) * (float)j / (float)(1 << t);
            float sn, cs; __sincosf(ang, &sn, &cs);
            cplx w1 = make_float2(cs, (float)SIGN * sn);
            cplx w3 = make_float2(cs * cs - sn * sn, 2.0f * cs * sn * (float)SIGN);
            // stage t-1
            cplx b1 = cmul(x1, w3);
            cplx q0 = make_float2(x0.x + b1.x, x0.y + b1.y);
            cplx q1 = make_float2(x0.x - b1.x, x0.y - b1.y);
            cplx b3 = cmul(x3, w3);
            cplx q2 = make_float2(x2.x + b3.x, x2.y + b3.y);
            cplx q3 = make_float2(x2.x - b3.x, x2.y - b3.y);
            // stage t
            cplx c2 = cmul(q2, w1);
            cplx c3 = rot90<SIGN>(cmul(q3, w1));
            A[a]         = make_float2(q0.x + c2.x, q0.y + c2.y);
            A[a + h]     = make_float2(q0.x - c2.x, q0.y - c2.y);
            A[a + Q]     = make_float2(q1.x + c3.x, q1.y + c3.y);
            A[a + h + Q] = make_float2(q1.x - c3.x, q1.y - c3.y);
        }
    }
    __syncthreads();
}

// scale_fn via explicit exp/log (powf is ~40 inst): 2*sigmoid(x)^log(10) + 1e-7
__device__ __forceinline__ float scale_fn(float x) {
    float s = 1.0f / (1.0f + __expf(-x));
    return 2.0f * __expf(2.3025851f * __logf(s)) + 1e-7f;
}

// --- fused: impulse partitions -> H[p] (blocks 0..7, scaled by 1/FFTN)
//            + pitch prefix (block 8) ---
__global__ __launch_bounds__(FTH) void k_ffth(const float* __restrict__ rn,
                                              const float* __restrict__ decay,
                                              const float* __restrict__ wet,
                                              const float* __restrict__ pitch,
                                              cplx* __restrict__ H,
                                              double* __restrict__ prefix) {
    __shared__ cplx sA[FFTN];
    int tid = threadIdx.x;
    if (blockIdx.x == NPART) {
        // exclusive prefix sum of pitch per batch (fp64), 8 serial chains
        if (tid < NBATCH) {
            double s = 0.0;
            const float* p = pitch + tid * NFRAME;
            double* o = prefix + tid * NFRAME;
            for (int f = 0; f < NFRAME; ++f) { o[f] = s; s += (double)p[f]; }
        }
        return;
    }
    int p = blockIdx.x;
    double c  = log1p(exp(-(double)decay[0])) * (500.0 / (double)SRATE);
    double wg = 1.0 / (1.0 + exp(-(double)wet[0]));
    for (int i = tid; i < FFTN; i += FTH) {
        float v = 0.0f;
        if (i < HOP) {
            int t = p * HOP + i;
            if (t == 0)         v = 1.0f;
            else if (t < SRATE) v = rn[t] * (float)(exp(-c * (double)t) * wg);
        }
        sA[i] = make_float2(v, 0.0f);
    }
    fft_dif_4096<-1>(sA, tid);     // sync at each stage top covers the staging writes
    const float s = 1.0f / (float)FFTN;     // fold IFFT scale into H
    for (int i = tid; i < FFTN; i += FTH) {
        cplx v = sA[i];
        H[p * FFTN + i] = make_float2(v.x * s, v.y * s);
    }
}

// --- fused per-(b,f) frame processing + harmonic synth -> signal ---
__global__ __launch_bounds__(128) void k_synth(const float* __restrict__ amp_param,
                                               const float* __restrict__ noise_param,
                                               const float* __restrict__ pitch,
                                               const float* __restrict__ noise,
                                               const double* __restrict__ prefix,
                                               float* __restrict__ sig) {
    __shared__ float s_famps[NHARM];   // normalized amps (phase-2 input)
    __shared__ float s_amps[NHARM];    // masked raw amps
    __shared__ float s_np[NBAND];
    __shared__ float s_ir[BLK];
    __shared__ float s_noise[BLK];
    __shared__ float s_red[BLK];       // reduction temps, then nz partials
    __shared__ float s_total;

    int bf = blockIdx.x;
    int tid = threadIdx.x;
    float pf = pitch[bf];

    if (tid < NHARM + 1) {
        float p = scale_fn(amp_param[bf * (NHARM + 1) + tid]);
        if (tid == 0) s_total = p;
        else {
            // aa = (pitch*k < sr/2) + 1e-4  -> 1.0001 or 0.0001, k = tid
            float aa = (pf * (float)tid < 8000.0f) ? 1.0001f : 0.0001f;
            s_amps[tid - 1] = p * aa;
        }
    }
    if (tid < NBAND) s_np[tid] = scale_fn(noise_param[bf * NBAND + tid] - 5.0f);
    s_noise[tid] = noise[bf * BLK + tid];
    __syncthreads();

    // ir[n] = (1/128)*(np[0] + 2*sum_{k=1}^{63} np[k] cos(2pi k n/128) + np[64] cos(pi n))
    //         * (0.5 + 0.5*cos(2pi n/128))    [roll/hann/roll collapsed]
    // 4 independent cosine chains: u_{k+4} = 2cos(4a)*u_k - u_{k-4}  (ILP for dep latency)
    float irv;
    {
        float ang = (float)(2.0 * PI_D / 128.0) * (float)tid;
        float sn, c; __sincosf(ang, &sn, &c);
        float tcc = 2.0f * c;
        float u1 = c;
        float u2 = fmaf(tcc, u1, -1.0f);
        float u3 = fmaf(tcc, u2, -u1);
        float u4 = fmaf(tcc, u3, -u2);
        float u5 = fmaf(tcc, u4, -u3);
        float u6 = fmaf(tcc, u5, -u4);
        float u7 = fmaf(tcc, u6, -u5);
        float t0 = s_np[4] * u4;
        float t1 = fmaf(s_np[5], u5, s_np[1] * u1);
        float t2 = fmaf(s_np[6], u6, s_np[2] * u2);
        float t3 = fmaf(s_np[7], u7, s_np[3] * u3);
        float cc4  = fmaf(2.0f * u2, u2, -1.0f);   // cos(4a)
        float tc4a = 2.0f * cc4;
        float A0 = 1.0f, A1 = u1, A2 = u2, A3 = u3;   // u_{k-8}
        float B0 = u4,   B1 = u5, B2 = u6, B3 = u7;   // u_{k-4}
        #pragma unroll
        for (int g = 0; g < 14; ++g) {                // k = 8+4g+i, i=0..3 -> 8..63
            float n0 = fmaf(tc4a, B0, -A0); t0 = fmaf(s_np[8 + 4 * g + 0], n0, t0); A0 = B0; B0 = n0;
            float n1 = fmaf(tc4a, B1, -A1); t1 = fmaf(s_np[8 + 4 * g + 1], n1, t1); A1 = B1; B1 = n1;
            float n2 = fmaf(tc4a, B2, -A2); t2 = fmaf(s_np[8 + 4 * g + 2], n2, t2); A2 = B2; B2 = n2;
            float n3 = fmaf(tc4a, B3, -A3); t3 = fmaf(s_np[8 + 4 * g + 3], n3, t3); A3 = B3; B3 = n3;
        }
        float u64 = fmaf(tc4a, B0, -A0);              // chain0 state: B0=u60, A0=u56
        float tt = (t0 + t1) + (t2 + t3);
        float a = fmaf(2.0f, tt, s_np[0]);
        a = fmaf(s_np[64], u64, a);
        a *= (1.0f / 128.0f);
        a *= fmaf(0.5f, c, 0.5f);
        irv = a;
    }

    // sum of masked amps (tree reduce over 128, entries >=100 are 0)
    s_red[tid] = (tid < NHARM) ? s_amps[tid] : 0.0f;
    __syncthreads();
    for (int s = 64; s > 0; s >>= 1) {
        if (tid < s) s_red[tid] += s_red[tid + s];
        __syncthreads();
    }
    float inv_red = s_red[0];
    __syncthreads();                   // s_red reads done; reuse as nz partials
    if (tid < NHARM) s_famps[tid] = s_amps[tid] / inv_red * s_total;
    s_ir[tid] = irv;
    __syncthreads();

    // nz[p] = sum_{m<=p} noise[m] * ir[p-m], balanced split, m unrolled x2 so
    // adjacent s_ir reads fuse into ds_read2_b32 (same FP order as before).
    float accA = 0.0f;
    {
        int p1 = tid, h1 = (p1 + 2) >> 1;          // ceil((p1+1)/2)
        int m = 0;
        for (; m + 1 < h1; m += 2) {
            float i0 = s_ir[p1 - m], i1 = s_ir[p1 - m - 1];
            accA = fmaf(s_noise[m], i0, accA);
            accA = fmaf(s_noise[m + 1], i1, accA);
        }
        if (m < h1) accA = fmaf(s_noise[m], s_ir[p1 - m], accA);
    }
    {
        int p2 = 127 - tid, h2 = (p2 + 2) >> 1;
        float accB = 0.0f;
        int m = h2;
        for (; m + 1 <= p2; m += 2) {
            float i0 = s_ir[p2 - m], i1 = s_ir[p2 - m - 1];
            accB = fmaf(s_noise[m], i0, accB);
            accB = fmaf(s_noise[m + 1], i1, accB);
        }
        if (m <= p2) accB = fmaf(s_noise[m], s_ir[p2 - m], accB);
        s_red[p2] = accB;
    }
    __syncthreads();
    float nzv = accA + s_red[tid];

    // harmonic synth: omega[n]/2pi = (128*prefix_excl + (r+1)*pitch)/sr; th = 2pi*frac
    // h = sum_k sin(k*th)*famps[k-1]; 4 independent sin chains:
    // s_{k+4} = 2cos(4th)*s_k - s_{k-4}  (seeds s1..s8)
    double q = (128.0 * prefix[bf] + (double)(tid + 1) * (double)pf) * (1.0 / 16000.0);
    float th = (float)(q - floor(q)) * (float)(2.0 * PI_D);  // exact for integer-k harmonics
    float h;
    {
        float s1v, c1v; __sincosf(th, &s1v, &c1v);
        float tc = 2.0f * c1v;
        float sk0 = s1v;                       // s1
        float sk1 = tc * s1v;                  // s2 (s0 = 0)
        float sk2 = fmaf(tc, sk1, -sk0);
        float sk3 = fmaf(tc, sk2, -sk1);
        float sk4 = fmaf(tc, sk3, -sk2);
        float sk5 = fmaf(tc, sk4, -sk3);
        float sk6 = fmaf(tc, sk5, -sk4);
        float sk7 = fmaf(tc, sk6, -sk5);
        float h0 = fmaf(sk4, s_famps[4], sk0 * s_famps[0]);
        float h1 = fmaf(sk5, s_famps[5], sk1 * s_famps[1]);
        float h2 = fmaf(sk6, s_famps[6], sk2 * s_famps[2]);
        float h3 = fmaf(sk7, s_famps[7], sk3 * s_famps[3]);
        float cs2 = fmaf(tc, c1v, -1.0f);      // cos(2th)
        float cs4 = fmaf(2.0f * cs2, cs2, -1.0f);
        float tc4 = 2.0f * cs4;
        float a0 = sk0, a1 = sk1, a2 = sk2, a3 = sk3;
        float b0 = sk4, b1 = sk5, b2 = sk6, b3 = sk7;
        #pragma unroll
        for (int g = 0; g < 23; ++g) {         // k = 9+4g+i, i=0..3 -> 9..100
            float n0 = fmaf(tc4, b0, -a0); h0 = fmaf(n0, s_famps[8 + 4 * g + 0], h0); a0 = b0; b0 = n0;
            float n1 = fmaf(tc4, b1, -a1); h1 = fmaf(n1, s_famps[8 + 4 * g + 1], h1); a1 = b1; b1 = n1;
            float n2 = fmaf(tc4, b2, -a2); h2 = fmaf(n2, s_famps[8 + 4 * g + 2], h2); a2 = b2; b2 = n2;
            float n3 = fmaf(tc4, b3, -a3); h3 = fmaf(n3, s_famps[8 + 4 * g + 3], h3); a3 = b3; b3 = n3;
        }
        h = (h0 + h1) + (h2 + h3);
    }
    sig[bf * BLK + tid] = h + nzv;
}

// --- FFT of packed signal frames: X[pb][m] = DIF_FFT(sigA + i*sigB over hop window) ---
__global__ __launch_bounds__(FTH) void k_fftsig(const float* __restrict__ sig,
                                                cplx* __restrict__ X) {
    __shared__ cplx sA[FFTN];
    int bm = blockIdx.x;
    int pb = bm / NHOPS, m = bm % NHOPS;
    int tid = threadIdx.x;
    const float* sa = sig + (2 * pb) * NSAMP;
    const float* sb = sa + NSAMP;
    int base = HOP * (m - 1);
    for (int i = tid; i < FFTN; i += FTH) {
        int idx = base + i;                      // idx < NSAMP guaranteed (m<=24)
        float va = 0.0f, vb = 0.0f;
        if (idx >= 0) { va = sa[idx]; vb = sb[idx]; }
        sA[i] = make_float2(va, vb);
    }
    fft_dif_4096<-1>(sA, tid);
    for (int i = tid; i < FFTN; i += FTH) X[bm * FFTN + i] = sA[i];
}

// --- Y = sum_p X[pb][m-p]*H[p] (digit-rev), IFFT, Re->batch 2pb, Im->batch 2pb+1 ---
__global__ __launch_bounds__(FTH) void k_specmac_ifft(const cplx* __restrict__ X,
                                                      const cplx* __restrict__ H,
                                                      float* __restrict__ out) {
    __shared__ cplx sA[FFTN];
    int bm = blockIdx.x;
    int pb = bm / NHOPS, m = bm % NHOPS;
    int tid = threadIdx.x;

    cplx acc[8];
    #pragma unroll
    for (int it = 0; it < 8; ++it) acc[it] = make_float2(0.0f, 0.0f);

    int pmax = (m < NPART - 1) ? m : (NPART - 1);
    for (int p = 0; p <= pmax; ++p) {
        const cplx* Xm = X + (pb * NHOPS + (m - p)) * FFTN;
        const cplx* Hp = H + p * FFTN;
        #pragma unroll
        for (int it = 0; it < 8; ++it) {
            int i = tid + (it << 9);
            cplx xv = Xm[i], hv = Hp[i];
            cplx pr = cmul(xv, hv);
            acc[it].x += pr.x; acc[it].y += pr.y;
        }
    }
    #pragma unroll
    for (int it = 0; it < 8; ++it) sA[tid + (it << 9)] = acc[it];

    fft_dit_4096<1>(sA, tid);      // digit-rev in -> natural out (scale folded into H)

    float* ob0 = out + (2 * pb) * NSAMP + m * HOP;
    float* ob1 = ob0 + NSAMP;
    #pragma unroll
    for (int it = 0; it < 4; ++it) {
        int j = tid + (it << 9);                 // [0,2048)
        cplx v = sA[HOP + j];                    // discard first half (overlap-save)
        ob0[j] = v.x;
        ob1[j] = v.y;
    }
}

extern "C" void kernel_launch(void* const* d_in, const int* in_sizes, int n_in,
                              void* d_out, int out_size, void* d_ws, size_t ws_size,
                              hipStream_t stream) {
    const float* amp_param   = (const float*)d_in[0];
    const float* noise_param = (const float*)d_in[1];
    const float* pitch       = (const float*)d_in[2];
    const float* noise       = (const float*)d_in[3];
    const float* rn          = (const float*)d_in[4];
    const float* decay       = (const float*)d_in[5];
    const float* wet         = (const float*)d_in[6];
    float* out = (float*)d_out;

    char* ws = (char*)d_ws;
    double* prefix = (double*)(ws + OFF_PREFIX);
    float*  sig    = (float*)(ws + OFF_SIG);
    cplx*   H      = (cplx*)(ws + OFF_H);
    cplx*   X      = (cplx*)(ws + OFF_X);

    k_ffth<<<dim3(NPART + 1), dim3(FTH), 0, stream>>>(rn, decay, wet, pitch, H, prefix);
    k_synth<<<dim3(NBATCH * NFRAME), dim3(128), 0, stream>>>(amp_param, noise_param, pitch, noise, prefix, sig);
    k_fftsig<<<dim3(NPAIR * NHOPS), dim3(FTH), 0, stream>>>(sig, X);
    k_specmac_ifft<<<dim3(NPAIR * NHOPS), dim3(FTH), 0, stream>>>(X, H, out);
}

// Round 14
// 43.650 us; speedup vs baseline: 6.2545x; 1.2215x over previous
//
#include <hip/hip_runtime.h>
#include <math.h>

#define NBATCH 8
#define NFRAME 400
#define NHARM  100
#define NBAND  65
#define SRATE  16000
#define BLK    128
#define NSAMP  (NFRAME*BLK)      // 51200 samples per batch
#define PI_D   3.14159265358979323846

// FFT convolution params: overlap-save, FFT 4096, hop 2048, 8 imp partitions.
// Two real batches packed per complex FFT (imp real => conv is complex-linear).
#define FFTN   4096
#define HOP    2048
#define NPART  8
#define NHOPS  (NSAMP / HOP)     // 25 per batch
#define NPAIR  (NBATCH / 2)      // 4 batch-pairs
#define FTH    1024              // threads per FFT block (latency-bound: 1 group/thread/pass)

// workspace layout (byte offsets, 8B aligned)
#define OFF_SIG    25600         // float[8*51200]           = 1638400 B
#define OFF_H      1729536       // float2[8][4096]          = 262144 B
#define OFF_X      1991680       // float2[4*25][4096]       = 3276800 B
// end 5268480 (~5.3 MB)

typedef float2 cplx;

__device__ __forceinline__ cplx cmul(cplx a, cplx b) {
    return make_float2(a.x * b.x - a.y * b.y, a.x * b.y + a.y * b.x);
}
// multiply by SIGN*i:  SIGN=-1: z*(-i) = (z.y, -z.x);  SIGN=+1: z*(+i) = (-z.y, z.x)
template <int SIGN>
__device__ __forceinline__ cplx rot90(cplx z) {
    return (SIGN < 0) ? make_float2(z.y, -z.x) : make_float2(-z.y, z.x);
}

// ---- 4096-pt in-place complex FFT in LDS, FTH=1024 threads, fused radix-2^2 ----
// One butterfly-group per thread per stage-pair (1024 groups).
// DIF (Gentleman-Sande): natural in -> digit-reversed out. SIGN=-1 forward.
template <int SIGN>
__device__ __forceinline__ void fft_dif_4096(cplx* A, int tid) {
    #pragma unroll
    for (int t = 12; t >= 2; t -= 2) {
        const int Q = 1 << (t - 2), h = 1 << (t - 1);
        __syncthreads();
        {
            int g = tid;                           // group idx [0,1024)
            int j = g & (Q - 1);
            int a = ((g >> (t - 2)) << t) + j;
            cplx x0 = A[a], x1 = A[a + Q], x2 = A[a + h], x3 = A[a + h + Q];
            float ang = (float)(2.0 * PI_D) * (float)j / (float)(1 << t);
            float sn, cs; __sincosf(ang, &sn, &cs);
            cplx w1 = make_float2(cs, (float)SIGN * sn);
            cplx w3 = make_float2(cs * cs - sn * sn, 2.0f * cs * sn * (float)SIGN);
            // stage t
            cplx p0 = make_float2(x0.x + x2.x, x0.y + x2.y);
            cplx p2 = cmul(make_float2(x0.x - x2.x, x0.y - x2.y), w1);
            cplx p1 = make_float2(x1.x + x3.x, x1.y + x3.y);
            cplx p3 = rot90<SIGN>(cmul(make_float2(x1.x - x3.x, x1.y - x3.y), w1));
            // stage t-1
            A[a]         = make_float2(p0.x + p1.x, p0.y + p1.y);
            A[a + Q]     = cmul(make_float2(p0.x - p1.x, p0.y - p1.y), w3);
            A[a + h]     = make_float2(p2.x + p3.x, p2.y + p3.y);
            A[a + h + Q] = cmul(make_float2(p2.x - p3.x, p2.y - p3.y), w3);
        }
    }
    __syncthreads();
}

// DIT (Cooley-Tukey): digit-reversed in -> natural out. SIGN=+1 inverse (unscaled).
template <int SIGN>
__device__ __forceinline__ void fft_dit_4096(cplx* A, int tid) {
    #pragma unroll
    for (int t = 2; t <= 12; t += 2) {
        const int Q = 1 << (t - 2), h = 1 << (t - 1);
        __syncthreads();
        {
            int g = tid;
            int j = g & (Q - 1);
            int a = ((g >> (t - 2)) << t) + j;
            cplx x0 = A[a], x1 = A[a + Q], x2 = A[a + h], x3 = A[a + h + Q];
            float ang = (float)(2.0 * PI_D) * (float)j / (float)(1 << t);
            float sn, cs; __sincosf(ang, &sn, &cs);
            cplx w1 = make_float2(cs, (float)SIGN * sn);
            cplx w3 = make_float2(cs * cs - sn * sn, 2.0f * cs * sn * (float)SIGN);
            // stage t-1
            cplx b1 = cmul(x1, w3);
            cplx q0 = make_float2(x0.x + b1.x, x0.y + b1.y);
            cplx q1 = make_float2(x0.x - b1.x, x0.y - b1.y);
            cplx b3 = cmul(x3, w3);
            cplx q2 = make_float2(x2.x + b3.x, x2.y + b3.y);
            cplx q3 = make_float2(x2.x - b3.x, x2.y - b3.y);
            // stage t
            cplx c2 = cmul(q2, w1);
            cplx c3 = rot90<SIGN>(cmul(q3, w1));
            A[a]         = make_float2(q0.x + c2.x, q0.y + c2.y);
            A[a + h]     = make_float2(q0.x - c2.x, q0.y - c2.y);
            A[a + Q]     = make_float2(q1.x + c3.x, q1.y + c3.y);
            A[a + h + Q] = make_float2(q1.x - c3.x, q1.y - c3.y);
        }
    }
    __syncthreads();
}

// scale_fn via explicit exp/log (powf is ~40 inst): 2*sigmoid(x)^log(10) + 1e-7
__device__ __forceinline__ float scale_fn(float x) {
    float s = 1.0f / (1.0f + __expf(-x));
    return 2.0f * __expf(2.3025851f * __logf(s)) + 1e-7f;
}

// --- fused per-(b,f) frame processing + harmonic synth -> signal ---
// Self-contained: pitch prefix computed per block via fp64 tree reduction.
__global__ __launch_bounds__(128) void k_synth(const float* __restrict__ amp_param,
                                               const float* __restrict__ noise_param,
                                               const float* __restrict__ pitch,
                                               const float* __restrict__ noise,
                                               float* __restrict__ sig) {
    __shared__ float s_famps[NHARM];   // normalized amps (phase-2 input)
    __shared__ float s_amps[NHARM];    // masked raw amps
    __shared__ float s_np[NBAND];
    __shared__ float s_ir[BLK];
    __shared__ float s_noise[BLK];
    __shared__ float s_red[BLK];       // reduction temps, then nz partials
    __shared__ double s_dred[BLK];     // fp64 prefix reduction
    __shared__ float s_total;

    int bf = blockIdx.x;
    int tid = threadIdx.x;
    int b  = bf / NFRAME, f0 = bf % NFRAME;
    float pf = pitch[bf];

    // prefix_excl = sum_{f < f0} pitch[b][f]  (fp64 tree reduce, <=4 loads/thread)
    {
        const float* prow = pitch + b * NFRAME;
        double ps = 0.0;
        for (int j = tid; j < f0; j += BLK) ps += (double)prow[j];
        s_dred[tid] = ps;
    }

    if (tid < NHARM + 1) {
        float p = scale_fn(amp_param[bf * (NHARM + 1) + tid]);
        if (tid == 0) s_total = p;
        else {
            // aa = (pitch*k < sr/2) + 1e-4  -> 1.0001 or 0.0001, k = tid
            float aa = (pf * (float)tid < 8000.0f) ? 1.0001f : 0.0001f;
            s_amps[tid - 1] = p * aa;
        }
    }
    if (tid < NBAND) s_np[tid] = scale_fn(noise_param[bf * NBAND + tid] - 5.0f);
    s_noise[tid] = noise[bf * BLK + tid];
    __syncthreads();

    // fold fp64 prefix reduction into the first sync ladder
    for (int s = 64; s > 0; s >>= 1) {
        if (tid < s) s_dred[tid] += s_dred[tid + s];
        __syncthreads();
    }
    double prefix_b = s_dred[0];

    // ir[n] = (1/128)*(np[0] + 2*sum_{k=1}^{63} np[k] cos(2pi k n/128) + np[64] cos(pi n))
    //         * (0.5 + 0.5*cos(2pi n/128))    [roll/hann/roll collapsed]
    // 4 independent cosine chains: u_{k+4} = 2cos(4a)*u_k - u_{k-4}  (ILP for dep latency)
    float irv;
    {
        float ang = (float)(2.0 * PI_D / 128.0) * (float)tid;
        float sn, c; __sincosf(ang, &sn, &c);
        float tcc = 2.0f * c;
        float u1 = c;
        float u2 = fmaf(tcc, u1, -1.0f);
        float u3 = fmaf(tcc, u2, -u1);
        float u4 = fmaf(tcc, u3, -u2);
        float u5 = fmaf(tcc, u4, -u3);
        float u6 = fmaf(tcc, u5, -u4);
        float u7 = fmaf(tcc, u6, -u5);
        float t0 = s_np[4] * u4;
        float t1 = fmaf(s_np[5], u5, s_np[1] * u1);
        float t2 = fmaf(s_np[6], u6, s_np[2] * u2);
        float t3 = fmaf(s_np[7], u7, s_np[3] * u3);
        float cc4  = fmaf(2.0f * u2, u2, -1.0f);   // cos(4a)
        float tc4a = 2.0f * cc4;
        float A0 = 1.0f, A1 = u1, A2 = u2, A3 = u3;   // u_{k-8}
        float B0 = u4,   B1 = u5, B2 = u6, B3 = u7;   // u_{k-4}
        #pragma unroll
        for (int g = 0; g < 14; ++g) {                // k = 8+4g+i, i=0..3 -> 8..63
            float n0 = fmaf(tc4a, B0, -A0); t0 = fmaf(s_np[8 + 4 * g + 0], n0, t0); A0 = B0; B0 = n0;
            float n1 = fmaf(tc4a, B1, -A1); t1 = fmaf(s_np[8 + 4 * g + 1], n1, t1); A1 = B1; B1 = n1;
            float n2 = fmaf(tc4a, B2, -A2); t2 = fmaf(s_np[8 + 4 * g + 2], n2, t2); A2 = B2; B2 = n2;
            float n3 = fmaf(tc4a, B3, -A3); t3 = fmaf(s_np[8 + 4 * g + 3], n3, t3); A3 = B3; B3 = n3;
        }
        float u64 = fmaf(tc4a, B0, -A0);              // chain0 state: B0=u60, A0=u56
        float tt = (t0 + t1) + (t2 + t3);
        float a = fmaf(2.0f, tt, s_np[0]);
        a = fmaf(s_np[64], u64, a);
        a *= (1.0f / 128.0f);
        a *= fmaf(0.5f, c, 0.5f);
        irv = a;
    }

    // sum of masked amps (tree reduce over 128, entries >=100 are 0)
    s_red[tid] = (tid < NHARM) ? s_amps[tid] : 0.0f;
    __syncthreads();
    for (int s = 64; s > 0; s >>= 1) {
        if (tid < s) s_red[tid] += s_red[tid + s];
        __syncthreads();
    }
    float inv_red = s_red[0];
    __syncthreads();                   // s_red reads done; reuse as nz partials
    if (tid < NHARM) s_famps[tid] = s_amps[tid] / inv_red * s_total;
    s_ir[tid] = irv;
    __syncthreads();

    // nz[p] = sum_{m<=p} noise[m] * ir[p-m], balanced split, m unrolled x2 so
    // adjacent s_ir reads fuse into ds_read2_b32 (same FP order as before).
    float accA = 0.0f;
    {
        int p1 = tid, h1 = (p1 + 2) >> 1;          // ceil((p1+1)/2)
        int m = 0;
        for (; m + 1 < h1; m += 2) {
            float i0 = s_ir[p1 - m], i1 = s_ir[p1 - m - 1];
            accA = fmaf(s_noise[m], i0, accA);
            accA = fmaf(s_noise[m + 1], i1, accA);
        }
        if (m < h1) accA = fmaf(s_noise[m], s_ir[p1 - m], accA);
    }
    {
        int p2 = 127 - tid, h2 = (p2 + 2) >> 1;
        float accB = 0.0f;
        int m = h2;
        for (; m + 1 <= p2; m += 2) {
            float i0 = s_ir[p2 - m], i1 = s_ir[p2 - m - 1];
            accB = fmaf(s_noise[m], i0, accB);
            accB = fmaf(s_noise[m + 1], i1, accB);
        }
        if (m <= p2) accB = fmaf(s_noise[m], s_ir[p2 - m], accB);
        s_red[p2] = accB;
    }
    __syncthreads();
    float nzv = accA + s_red[tid];

    // harmonic synth: omega[n]/2pi = (128*prefix_excl + (r+1)*pitch)/sr; th = 2pi*frac
    // h = sum_k sin(k*th)*famps[k-1]; 4 independent sin chains:
    // s_{k+4} = 2cos(4th)*s_k - s_{k-4}  (seeds s1..s8)
    double q = (128.0 * prefix_b + (double)(tid + 1) * (double)pf) * (1.0 / 16000.0);
    float th = (float)(q - floor(q)) * (float)(2.0 * PI_D);  // exact for integer-k harmonics
    float h;
    {
        float s1v, c1v; __sincosf(th, &s1v, &c1v);
        float tc = 2.0f * c1v;
        float sk0 = s1v;                       // s1
        float sk1 = tc * s1v;                  // s2 (s0 = 0)
        float sk2 = fmaf(tc, sk1, -sk0);
        float sk3 = fmaf(tc, sk2, -sk1);
        float sk4 = fmaf(tc, sk3, -sk2);
        float sk5 = fmaf(tc, sk4, -sk3);
        float sk6 = fmaf(tc, sk5, -sk4);
        float sk7 = fmaf(tc, sk6, -sk5);
        float h0 = fmaf(sk4, s_famps[4], sk0 * s_famps[0]);
        float h1 = fmaf(sk5, s_famps[5], sk1 * s_famps[1]);
        float h2 = fmaf(sk6, s_famps[6], sk2 * s_famps[2]);
        float h3 = fmaf(sk7, s_famps[7], sk3 * s_famps[3]);
        float cs2 = fmaf(tc, c1v, -1.0f);      // cos(2th)
        float cs4 = fmaf(2.0f * cs2, cs2, -1.0f);
        float tc4 = 2.0f * cs4;
        float a0 = sk0, a1 = sk1, a2 = sk2, a3 = sk3;
        float b0 = sk4, b1 = sk5, b2 = sk6, b3 = sk7;
        #pragma unroll
        for (int g = 0; g < 23; ++g) {         // k = 9+4g+i, i=0..3 -> 9..100
            float n0 = fmaf(tc4, b0, -a0); h0 = fmaf(n0, s_famps[8 + 4 * g + 0], h0); a0 = b0; b0 = n0;
            float n1 = fmaf(tc4, b1, -a1); h1 = fmaf(n1, s_famps[8 + 4 * g + 1], h1); a1 = b1; b1 = n1;
            float n2 = fmaf(tc4, b2, -a2); h2 = fmaf(n2, s_famps[8 + 4 * g + 2], h2); a2 = b2; b2 = n2;
            float n3 = fmaf(tc4, b3, -a3); h3 = fmaf(n3, s_famps[8 + 4 * g + 3], h3); a3 = b3; b3 = n3;
        }
        h = (h0 + h1) + (h2 + h3);
    }
    sig[bf * BLK + tid] = h + nzv;
}

// --- FFT of packed signal frames (blocks 0..99): X[pb][m] = DIF_FFT(sigA + i*sigB)
//     + impulse-partition FFTs (blocks 100..107): H[p], scaled by 1/FFTN ---
__global__ __launch_bounds__(FTH) void k_fftsig(const float* __restrict__ sig,
                                                const float* __restrict__ rn,
                                                const float* __restrict__ decay,
                                                const float* __restrict__ wet,
                                                cplx* __restrict__ X,
                                                cplx* __restrict__ H) {
    __shared__ cplx sA[FFTN];
    int bm = blockIdx.x;
    int tid = threadIdx.x;

    if (bm >= NPAIR * NHOPS) {
        // impulse partition p
        int p = bm - NPAIR * NHOPS;
        double c  = log1p(exp(-(double)decay[0])) * (500.0 / (double)SRATE);
        double wg = 1.0 / (1.0 + exp(-(double)wet[0]));
        for (int i = tid; i < FFTN; i += FTH) {
            float v = 0.0f;
            if (i < HOP) {
                int t = p * HOP + i;
                if (t == 0)         v = 1.0f;
                else if (t < SRATE) v = rn[t] * (float)(exp(-c * (double)t) * wg);
            }
            sA[i] = make_float2(v, 0.0f);
        }
        fft_dif_4096<-1>(sA, tid);
        const float s = 1.0f / (float)FFTN;     // fold IFFT scale into H
        for (int i = tid; i < FFTN; i += FTH) {
            cplx v = sA[i];
            H[p * FFTN + i] = make_float2(v.x * s, v.y * s);
        }
        return;
    }

    int pb = bm / NHOPS, m = bm % NHOPS;
    const float* sa = sig + (2 * pb) * NSAMP;
    const float* sb = sa + NSAMP;
    int base = HOP * (m - 1);
    for (int i = tid; i < FFTN; i += FTH) {
        int idx = base + i;                      // idx < NSAMP guaranteed (m<=24)
        float va = 0.0f, vb = 0.0f;
        if (idx >= 0) { va = sa[idx]; vb = sb[idx]; }
        sA[i] = make_float2(va, vb);
    }
    fft_dif_4096<-1>(sA, tid);
    for (int i = tid; i < FFTN; i += FTH) X[bm * FFTN + i] = sA[i];
}

// --- Y = sum_p X[pb][m-p]*H[p] (digit-rev), IFFT, Re->batch 2pb, Im->batch 2pb+1 ---
__global__ __launch_bounds__(FTH) void k_specmac_ifft(const cplx* __restrict__ X,
                                                      const cplx* __restrict__ H,
                                                      float* __restrict__ out) {
    __shared__ cplx sA[FFTN];
    int bm = blockIdx.x;
    int pb = bm / NHOPS, m = bm % NHOPS;
    int tid = threadIdx.x;

    cplx acc[4];
    #pragma unroll
    for (int it = 0; it < 4; ++it) acc[it] = make_float2(0.0f, 0.0f);

    int pmax = (m < NPART - 1) ? m : (NPART - 1);
    for (int p = 0; p <= pmax; ++p) {
        const cplx* Xm = X + (pb * NHOPS + (m - p)) * FFTN;
        const cplx* Hp = H + p * FFTN;
        #pragma unroll
        for (int it = 0; it < 4; ++it) {
            int i = tid + (it << 10);
            cplx xv = Xm[i], hv = Hp[i];
            cplx pr = cmul(xv, hv);
            acc[it].x += pr.x; acc[it].y += pr.y;
        }
    }
    #pragma unroll
    for (int it = 0; it < 4; ++it) sA[tid + (it << 10)] = acc[it];

    fft_dit_4096<1>(sA, tid);      // digit-rev in -> natural out (scale folded into H)

    float* ob0 = out + (2 * pb) * NSAMP + m * HOP;
    float* ob1 = ob0 + NSAMP;
    #pragma unroll
    for (int it = 0; it < 2; ++it) {
        int j = tid + (it << 10);                // [0,2048)
        cplx v = sA[HOP + j];                    // discard first half (overlap-save)
        ob0[j] = v.x;
        ob1[j] = v.y;
    }
}

extern "C" void kernel_launch(void* const* d_in, const int* in_sizes, int n_in,
                              void* d_out, int out_size, void* d_ws, size_t ws_size,
                              hipStream_t stream) {
    const float* amp_param   = (const float*)d_in[0];
    const float* noise_param = (const float*)d_in[1];
    const float* pitch       = (const float*)d_in[2];
    const float* noise       = (const float*)d_in[3];
    const float* rn          = (const float*)d_in[4];
    const float* decay       = (const float*)d_in[5];
    const float* wet         = (const float*)d_in[6];
    float* out = (float*)d_out;

    char* ws = (char*)d_ws;
    float*  sig    = (float*)(ws + OFF_SIG);
    cplx*   H      = (cplx*)(ws + OFF_H);
    cplx*   X      = (cplx*)(ws + OFF_X);

    k_synth<<<dim3(NBATCH * NFRAME), dim3(128), 0, stream>>>(amp_param, noise_param, pitch, noise, sig);
    k_fftsig<<<dim3(NPAIR * NHOPS + NPART), dim3(FTH), 0, stream>>>(sig, rn, decay, wet, X, H);
    k_specmac_ifft<<<dim3(NPAIR * NHOPS), dim3(FTH), 0, stream>>>(X, H, out);
}